// Round 5
// baseline (693.749 us; speedup 1.0000x reference)
//
#include <hip/hip_runtime.h>
#include <hip/hip_bf16.h>
#include <math.h>

#define N_NODES 10000
#define N_EDGES 160000
#define SBLK 157            // ceil(10000/64) s-GEMM blocks
#define VBLK 469            // ceil(30000/64) v-GEMM blocks

typedef __attribute__((ext_vector_type(8))) short short8x;
typedef __attribute__((ext_vector_type(4))) float floatx4;

union S8 { short8x v; unsigned short u[8]; uint4 q; };

__device__ __forceinline__ unsigned short f2bf(float x) {
    unsigned int u = __float_as_uint(x);
    return (unsigned short)((u + 0x7fffu + ((u >> 16) & 1u)) >> 16);
}
__device__ __forceinline__ float bf2f(unsigned short u) {
    return __uint_as_float(((unsigned)u) << 16);
}
__device__ __forceinline__ float silu_c(float x) {
    return 1.679f * x / (1.0f + __expf(-x));
}

// ---------------- Kernel A: y = lin1(node_feats), layout y[n][u][4]={s,v0,v1,v2} ----------------
__global__ __launch_bounds__(256) void node_lin1(
    const float* __restrict__ node_feats,
    const float* __restrict__ lin1_ws,
    const float* __restrict__ lin1_wv,
    float* __restrict__ y)
{
    __shared__ float xf[16 * 520];
    const int blk = blockIdx.x;      // 625
    const int t = threadIdx.x;
    const int base = blk * 16;

    const float4* nf4 = (const float4*)(node_feats + (size_t)base * 512);
    #pragma unroll
    for (int r = 0; r < 8; r++) {
        int i4 = r * 256 + t;
        int flat = i4 * 4;
        int n = flat >> 9;
        int off = flat & 511;
        *(float4*)&xf[n * 520 + off] = nf4[i4];
    }
    __syncthreads();

    const int n_loc = t >> 4;
    const int w0 = (t & 15) * 8;
    float as[8];
    float av[8][3];
    #pragma unroll
    for (int j = 0; j < 8; j++) { as[j] = 0.f; av[j][0] = 0.f; av[j][1] = 0.f; av[j][2] = 0.f; }

    const float* xrow = &xf[n_loc * 520];
    #pragma unroll 1
    for (int u = 0; u < 128; u++) {
        float xs  = xrow[u];
        float xv0 = xrow[128 + u*3 + 0];
        float xv1 = xrow[128 + u*3 + 1];
        float xv2 = xrow[128 + u*3 + 2];
        float ws[8], wvv[8];
        *(float4*)&ws[0] = *(const float4*)&lin1_ws[u*128 + w0];
        *(float4*)&ws[4] = *(const float4*)&lin1_ws[u*128 + w0 + 4];
        *(float4*)&wvv[0] = *(const float4*)&lin1_wv[u*128 + w0];
        *(float4*)&wvv[4] = *(const float4*)&lin1_wv[u*128 + w0 + 4];
        #pragma unroll
        for (int j = 0; j < 8; j++) {
            as[j]    += xs  * ws[j];
            av[j][0] += xv0 * wvv[j];
            av[j][1] += xv1 * wvv[j];
            av[j][2] += xv2 * wvv[j];
        }
    }

    const float l1 = 0.0883883476483f;  // 1/sqrt(128)
    const int node = base + n_loc;
    float* yrow = y + (size_t)node * 512;
    #pragma unroll
    for (int j = 0; j < 8; j++) {
        float4 o = make_float4(as[j] * l1, av[j][0] * l1, av[j][1] * l1, av[j][2] * l1);
        *(float4*)&yrow[(w0 + j) * 4] = o;
    }
}

// ---------------- CSR build ----------------
__global__ __launch_bounds__(256) void hist_kernel(const int* __restrict__ edge_index,
                                                   int* __restrict__ deg) {
    int e = blockIdx.x * 256 + threadIdx.x;
    if (e < N_EDGES) atomicAdd(&deg[edge_index[e]], 1);
}

__global__ __launch_bounds__(1024) void scan_kernel(const int* __restrict__ deg,
                                                    int* __restrict__ row_start,
                                                    int* __restrict__ cursor) {
    __shared__ int wsum[16];
    __shared__ int carry_s;
    const int t = threadIdx.x;        // 0..1023
    const int lane = t & 63, w = t >> 6;
    if (t == 0) carry_s = 0;
    __syncthreads();
    for (int chunk = 0; chunk < 10; chunk++) {
        int idx = chunk * 1024 + t;
        int v = (idx < N_NODES) ? deg[idx] : 0;
        int x = v;
        #pragma unroll
        for (int off = 1; off < 64; off <<= 1) {
            int yv = __shfl_up(x, off, 64);
            if (lane >= off) x += yv;
        }
        if (lane == 63) wsum[w] = x;
        __syncthreads();
        int wpre = 0;
        for (int i = 0; i < w; i++) wpre += wsum[i];
        int incl = x + wpre + carry_s;
        int excl = incl - v;
        if (idx < N_NODES) { row_start[idx] = excl; cursor[idx] = excl; }
        __syncthreads();
        if (t == 1023) carry_s = incl;
        __syncthreads();
    }
    if (t == 0) row_start[N_NODES] = carry_s;
}

__global__ __launch_bounds__(256) void scatter_kernel(const int* __restrict__ edge_index,
                                                      int* __restrict__ cursor,
                                                      int* __restrict__ edge_list) {
    int e = blockIdx.x * 256 + threadIdx.x;
    if (e < N_EDGES) {
        int pos = atomicAdd(&cursor[edge_index[e]], 1);
        edge_list[pos] = e;
    }
}

// ---------------- pack_w2a: w2/8 -> bf16, MFMA A-fragment order (A = w2^T) ----------------
__global__ __launch_bounds__(256) void pack_w2a_kernel(
    const float* __restrict__ fc_w2, unsigned short* __restrict__ w2a)
{
    int id = blockIdx.x * 256 + threadIdx.x;   // 0..4095
    int lane = id & 63;
    int mfg = (id >> 6) & 31;
    int ks = id >> 11;
    int col = mfg * 16 + (lane & 15);
    int k0 = ks * 32 + (lane >> 4) * 8;
    S8 pk;
    #pragma unroll
    for (int j = 0; j < 8; j++)
        pk.u[j] = f2bf(fc_w2[(k0 + j) * 512 + col] * 0.125f);
    *(uint4*)(w2a + (size_t)id * 8) = pk.q;
}

// ---------------- Kernel B1: edge MLP, layer3 via MFMA -> planar bf16 w ----------------
// w_planes[comp][e][u], comp in {ss, sv, vs, vv}
// Epilogue: per-comp LDS transpose + fully-coalesced 16 KB contiguous block store.
__global__ __launch_bounds__(256) void edge_w_mfma(
    const float* __restrict__ edge_feats,
    const float* __restrict__ fc_w0,
    const float* __restrict__ fc_w1,
    const unsigned short* __restrict__ w2a,
    unsigned short* __restrict__ w_planes)
{
    // LDS union: phases use ef/h0/h1b; epilogue reuses the (dead) ef+h0 region
    // as a 64 x 130 ushort staging tile (16,640 B <= 2304+17408).
    __shared__ __align__(16) unsigned char smem[29184];
    float* ef = (float*)smem;                                    // 64*9*4   = 2304
    float* h0 = (float*)(smem + 2304);                           // 64*68*4  = 17408
    unsigned short* h1b = (unsigned short*)(smem + 2304 + 17408);// 64*72*2  = 9216
    unsigned short* tile = (unsigned short*)smem;                // 64*130*2 = 16640 (epilogue)

    const int blk = blockIdx.x;      // 2500
    const int t = threadIdx.x;
    const int eb0 = blk * 64;

    // stage edge_feats (64 x 8)
    #pragma unroll
    for (int r = 0; r < 2; r++) {
        int idx = r * 256 + t;
        ef[(idx >> 3) * 9 + (idx & 7)] = edge_feats[(size_t)eb0 * 8 + idx];
    }
    __syncthreads();

    const int e_loc = t >> 2;
    const int c0 = (t & 3) * 16;

    // phase 1: h0 = silu_c(ef @ w0 / sqrt(8))
    {
        float a0[16];
        #pragma unroll
        for (int i = 0; i < 16; i++) a0[i] = 0.f;
        const float* efr = &ef[e_loc * 9];
        #pragma unroll
        for (int k = 0; k < 8; k++) {
            float ek = efr[k];
            float w[16];
            #pragma unroll
            for (int q4 = 0; q4 < 4; q4++)
                *(float4*)&w[q4*4] = *(const float4*)&fc_w0[k*64 + c0 + q4*4];
            #pragma unroll
            for (int i = 0; i < 16; i++) a0[i] += ek * w[i];
        }
        const float is8 = 0.35355339059f;
        #pragma unroll
        for (int i = 0; i < 16; i++)
            h0[e_loc * 68 + c0 + i] = silu_c(a0[i] * is8);
    }
    __syncthreads();

    // phase 2: h1 = silu_c(h0 @ w1 / 8), stored bf16 into h1b[e][k]
    {
        float a1[16];
        #pragma unroll
        for (int i = 0; i < 16; i++) a1[i] = 0.f;
        const float* h0r = &h0[e_loc * 68];
        #pragma unroll 1
        for (int k = 0; k < 64; k++) {
            float hk = h0r[k];
            float w[16];
            #pragma unroll
            for (int q4 = 0; q4 < 4; q4++)
                *(float4*)&w[q4*4] = *(const float4*)&fc_w1[k*64 + c0 + q4*4];
            #pragma unroll
            for (int i = 0; i < 16; i++) a1[i] += hk * w[i];
        }
        S8 p0, p1;
        #pragma unroll
        for (int i = 0; i < 8; i++) {
            p0.u[i] = f2bf(silu_c(a1[i] * 0.125f));
            p1.u[i] = f2bf(silu_c(a1[8 + i] * 0.125f));
        }
        *(uint4*)&h1b[e_loc * 72 + c0]     = p0.q;
        *(uint4*)&h1b[e_loc * 72 + c0 + 8] = p1.q;
    }
    __syncthreads();

    // phase 3: W_block = w2^T(bf16, /8 folded) @ h1^T  via MFMA
    // D[m=outcol][n=edge]; wave wv owns cols wv*128..wv*128+127 -> component wv
    const int lane = t & 63;
    const int wv = t >> 6;
    const int quad = lane >> 4;
    const int m15 = lane & 15;

    floatx4 c[8][4];   // [mf][ee]
    #pragma unroll
    for (int mf = 0; mf < 8; mf++)
        #pragma unroll
        for (int ee = 0; ee < 4; ee++)
            c[mf][ee] = (floatx4){0.f, 0.f, 0.f, 0.f};

    const uint4* w2aq = (const uint4*)w2a;
    #pragma unroll
    for (int ks = 0; ks < 2; ks++) {
        S8 bfr[4];
        #pragma unroll
        for (int ee = 0; ee < 4; ee++)
            bfr[ee].q = *(const uint4*)&h1b[(ee*16 + m15) * 72 + ks*32 + quad*8];
        #pragma unroll
        for (int mf = 0; mf < 8; mf++) {
            S8 afr;
            afr.q = w2aq[(size_t)(ks*32 + wv*8 + mf) * 64 + lane];
            #pragma unroll
            for (int ee = 0; ee < 4; ee++)
                c[mf][ee] = __builtin_amdgcn_mfma_f32_16x16x32_bf16(afr.v, bfr[ee].v, c[mf][ee], 0, 0, 0);
        }
    }

    // epilogue: 4 rounds; round r: wave r dumps its 64x128 tile to LDS,
    // then all 256 threads store the contiguous 16 KB plane slice.
    // c[mf][ee][i] = w[col = mf*16 + quad*4 + i][edge = ee*16 + m15]
    #pragma unroll 1
    for (int round = 0; round < 4; round++) {
        __syncthreads();   // previous round's tile reads done / MFMA regs ready
        if (wv == round) {
            #pragma unroll
            for (int mf = 0; mf < 8; mf++) {
                #pragma unroll
                for (int ee = 0; ee < 4; ee++) {
                    ushort4 pk = make_ushort4(f2bf(c[mf][ee][0]), f2bf(c[mf][ee][1]),
                                              f2bf(c[mf][ee][2]), f2bf(c[mf][ee][3]));
                    *(ushort4*)&tile[(ee*16 + m15)*130 + mf*16 + quad*4] = pk;
                }
            }
        }
        __syncthreads();
        unsigned short* dstp = w_planes + (size_t)round * N_EDGES * 128 + (size_t)eb0 * 128;
        #pragma unroll
        for (int it = 0; it < 4; it++) {
            int idx = it * 256 + t;          // 0..1023
            int e  = idx >> 4;
            int ch = idx & 15;
            uint4 vtmp = *(const uint4*)&tile[e*130 + ch*8];
            *(uint4*)&dstp[(size_t)idx * 8] = vtmp;   // byte offset 16*idx: contiguous
        }
    }
}

// ---------------- Kernel B2: per-node gather (no atomics, planar w) ----------------
__global__ __launch_bounds__(256) void gather_kernel(
    const int* __restrict__ row_start,
    const int* __restrict__ edge_list,
    const int* __restrict__ edge_index,
    const float* __restrict__ edge_attrs,
    const unsigned short* __restrict__ w_planes,
    const float* __restrict__ y,
    float* __restrict__ acc)
{
    const int t = threadIdx.x;
    const int half = t >> 7;
    const int u = t & 127;
    const int n = blockIdx.x * 2 + half;   // 5000 blocks
    const int sbeg = row_start[n];
    const int send = row_start[n + 1];

    float aS0 = 0.f, aS1 = 0.f;
    float aV2x = 0.f, aV2y = 0.f, aV2z = 0.f;
    float aV3x = 0.f, aV3y = 0.f, aV3z = 0.f;

    const unsigned short* pss = w_planes;
    const unsigned short* psv = w_planes + (size_t)1 * N_EDGES * 128;
    const unsigned short* pvs = w_planes + (size_t)2 * N_EDGES * 128;
    const unsigned short* pvv = w_planes + (size_t)3 * N_EDGES * 128;

    for (int i = sbeg; i < send; i++) {
        int e = edge_list[i];
        int src = edge_index[N_EDGES + e];
        size_t eo = (size_t)e * 128 + u;
        float wss = bf2f(pss[eo]);
        float wsv = bf2f(psv[eo]);
        float wvs = bf2f(pvs[eo]);
        float wvv = bf2f(pvv[eo]);
        float4 qv = *(const float4*)(y + (size_t)src * 512 + u * 4);
        float4 ea = *(const float4*)(edge_attrs + (size_t)e * 4);
        aS0 += wss * qv.x * ea.x;
        aS1 += wvv * (qv.y*ea.y + qv.z*ea.z + qv.w*ea.w);
        float tsv = wsv * qv.x;
        aV2x += tsv * ea.y; aV2y += tsv * ea.z; aV2z += tsv * ea.w;
        float tvs = wvs * ea.x;
        aV3x += tvs * qv.y; aV3y += tvs * qv.z; aV3z += tvs * qv.w;
    }

    const float inv = 0.25f;                 // 1/sqrt(16)
    const float s1c = 0.57735026919f * 0.25f;
    float* a = acc + (size_t)n * 1024;
    a[u] = aS0 * inv;
    a[128 + u] = aS1 * s1c;
    a[256 + u*3 + 0] = aV2x * inv;
    a[256 + u*3 + 1] = aV2y * inv;
    a[256 + u*3 + 2] = aV2z * inv;
    a[256 + (128 + u)*3 + 0] = aV3x * inv;
    a[256 + (128 + u)*3 + 1] = aV3y * inv;
    a[256 + (128 + u)*3 + 2] = aV3z * inv;
}

// ---------------- pack_b: B matrices -> bf16, MFMA B-fragment order ----------------
__global__ __launch_bounds__(256) void pack_b_kernel(
    const float* __restrict__ sc_ws, const float* __restrict__ lin2_ws,
    const float* __restrict__ sc_wv, const float* __restrict__ lin2_wv,
    unsigned short* __restrict__ b_pre)
{
    int id = blockIdx.x * 256 + threadIdx.x;     // 0..49151
    int mat = id / 24576;
    int slot = id - mat * 24576;
    int ks = slot >> 9;
    int rr = slot & 511;
    int lane = rr & 63;
    int quad = lane >> 4;
    int n = ((rr >> 6) << 4) + (lane & 15);
    const float* sc  = mat ? sc_wv  : sc_ws;
    const float* lin = mat ? lin2_wv : lin2_ws;
    S8 pk;
    #pragma unroll
    for (int j = 0; j < 8; j++) {
        int k = ks * 32 + quad * 8 + j;
        float w;
        if (k < 1280) {
            int u = k & 127, v = k >> 7;
            w = sc[(u * 10 + v) * 128 + n];
        } else {
            w = lin[(k - 1280) * 128 + n];
        }
        pk.u[j] = f2bf(w);
    }
    *(uint4*)(b_pre + (size_t)id * 8) = pk.q;
}

// ---------------- node_out as MFMA GEMM ----------------
__global__ __launch_bounds__(256) void node_out_mfma(
    const float* __restrict__ node_feats,
    const float* __restrict__ node_attrs,
    const float* __restrict__ acc,
    const unsigned short* __restrict__ b_pre,
    float* __restrict__ out)
{
    __shared__ short8x Al[256];     // 64 rows x 32 k, fragment-order packed (4 KB)
    const int bid = blockIdx.x;
    const int t = threadIdx.x;
    const int lane = t & 63;
    const int wv = t >> 6;
    const bool is_s = (bid < SBLK);

    const int r = t >> 2;
    const int q = t & 3;
    int node, comp, st;
    if (is_s) {
        int R = bid * 64 + r;
        node = (R < N_NODES) ? R : 0;
        comp = 0; st = 1;
    } else {
        int Rg = (bid - SBLK) * 64 + r;
        if (Rg >= 3 * N_NODES) Rg = 0;
        comp = Rg / N_NODES;
        node = Rg - comp * N_NODES;
        st = 3;
    }
    const float* px = is_s ? (node_feats + (size_t)node * 512)
                           : (node_feats + (size_t)node * 512 + 128 + comp);
    const float* pa = is_s ? (acc + (size_t)node * 1024)
                           : (acc + (size_t)node * 1024 + 256 + comp);
    const float* pattr = node_attrs + node * 10;

    const int a_slot = ((r >> 4) << 6) + (q << 4) + (r & 15);
    const uint4* bfrag_base = (const uint4*)(b_pre) + (is_s ? 0 : 24576);

    const float sc_norm = 0.02795084972f;   // 1/sqrt(1280)
    const float l2 = 0.0625f;               // 1/sqrt(256)

    floatx4 c[4][2];
    #pragma unroll
    for (int af = 0; af < 4; af++) {
        c[af][0] = (floatx4){0.f, 0.f, 0.f, 0.f};
        c[af][1] = (floatx4){0.f, 0.f, 0.f, 0.f};
    }

    for (int ks = 0; ks < 48; ks++) {
        S8 b0, b1;
        b0.q = bfrag_base[ks*512 + (wv*2+0)*64 + lane];
        b1.q = bfrag_base[ks*512 + (wv*2+1)*64 + lane];

        __syncthreads();
        {
            int k0 = ks * 32 + q * 8;
            S8 pk;
            if (k0 < 1280) {
                int u0 = k0 & 127;
                int v  = k0 >> 7;
                float att = pattr[v] * sc_norm;
                #pragma unroll
                for (int j = 0; j < 8; j++)
                    pk.u[j] = f2bf(px[(u0 + j) * st] * att);
            } else {
                int j2 = k0 - 1280;
                #pragma unroll
                for (int j = 0; j < 8; j++)
                    pk.u[j] = f2bf(pa[(j2 + j) * st] * l2);
            }
            Al[a_slot] = pk.v;
        }
        __syncthreads();

        short8x a0 = Al[lane];
        short8x a1 = Al[64 + lane];
        short8x a2 = Al[128 + lane];
        short8x a3 = Al[192 + lane];
        c[0][0] = __builtin_amdgcn_mfma_f32_16x16x32_bf16(a0, b0.v, c[0][0], 0, 0, 0);
        c[0][1] = __builtin_amdgcn_mfma_f32_16x16x32_bf16(a0, b1.v, c[0][1], 0, 0, 0);
        c[1][0] = __builtin_amdgcn_mfma_f32_16x16x32_bf16(a1, b0.v, c[1][0], 0, 0, 0);
        c[1][1] = __builtin_amdgcn_mfma_f32_16x16x32_bf16(a1, b1.v, c[1][1], 0, 0, 0);
        c[2][0] = __builtin_amdgcn_mfma_f32_16x16x32_bf16(a2, b0.v, c[2][0], 0, 0, 0);
        c[2][1] = __builtin_amdgcn_mfma_f32_16x16x32_bf16(a2, b1.v, c[2][1], 0, 0, 0);
        c[3][0] = __builtin_amdgcn_mfma_f32_16x16x32_bf16(a3, b0.v, c[3][0], 0, 0, 0);
        c[3][1] = __builtin_amdgcn_mfma_f32_16x16x32_bf16(a3, b1.v, c[3][1], 0, 0, 0);
    }

    const int m = lane & 15;
    const int rq = (lane >> 4) * 4;
    if (is_s) {
        const int n0 = bid * 64;
        #pragma unroll
        for (int af = 0; af < 4; af++) {
            #pragma unroll
            for (int i = 0; i < 4; i++) {
                int n = n0 + af*16 + rq + i;
                if (n < N_NODES) {
                    out[(size_t)n*512 + wv*32 + m]      = c[af][0][i];
                    out[(size_t)n*512 + wv*32 + 16 + m] = c[af][1][i];
                }
            }
        }
    } else {
        const int r0 = (bid - SBLK) * 64;
        #pragma unroll
        for (int af = 0; af < 4; af++) {
            #pragma unroll
            for (int i = 0; i < 4; i++) {
                int Rg = r0 + af*16 + rq + i;
                if (Rg < 3 * N_NODES) {
                    int cc = Rg / N_NODES;
                    int nn = Rg - cc * N_NODES;
                    float* po = out + (size_t)nn*512 + 128 + cc;
                    po[(wv*32 + m)*3]      = c[af][0][i];
                    po[(wv*32 + 16 + m)*3] = c[af][1][i];
                }
            }
        }
    }
}

extern "C" void kernel_launch(void* const* d_in, const int* in_sizes, int n_in,
                              void* d_out, int out_size, void* d_ws, size_t ws_size,
                              hipStream_t stream) {
    const float* node_feats = (const float*)d_in[0];
    const float* node_attrs = (const float*)d_in[1];
    const float* edge_feats = (const float*)d_in[2];
    const float* edge_attrs = (const float*)d_in[3];
    const int*   edge_index = (const int*)  d_in[4];
    const float* lin1_ws    = (const float*)d_in[5];
    const float* lin1_wv    = (const float*)d_in[6];
    const float* fc_w0      = (const float*)d_in[7];
    const float* fc_w1      = (const float*)d_in[8];
    const float* fc_w2      = (const float*)d_in[9];
    const float* lin2_ws    = (const float*)d_in[10];
    const float* lin2_wv    = (const float*)d_in[11];
    const float* sc_ws      = (const float*)d_in[12];
    const float* sc_wv      = (const float*)d_in[13];
    float* out = (float*)d_out;

    // workspace layout
    float* y   = (float*)d_ws;                        //  5,120,000 f32
    float* acc = y + (size_t)N_NODES * 512;           // 10,240,000 f32
    unsigned short* w_planes = (unsigned short*)(acc + (size_t)N_NODES * 1024); // 4*160000*128 bf16
    int* deg       = (int*)(w_planes + (size_t)4 * N_EDGES * 128);
    int* row_start = deg + 10016;
    int* cursor    = row_start + 10016;
    int* edge_list = cursor + 10016;
    unsigned short* b_pre = (unsigned short*)(edge_list + N_EDGES); // 2*24576*8 bf16
    unsigned short* w2a   = b_pre + (size_t)2 * 24576 * 8;          // 4096*8 bf16
    const size_t need = (size_t)(5120000 + 10240000) * 4 + (size_t)4 * N_EDGES * 128 * 2
                      + (size_t)(10016 * 3 + N_EDGES) * 4
                      + ((size_t)2 * 24576 * 8 + (size_t)4096 * 8) * 2;
    if (ws_size < need) return;

    hipLaunchKernelGGL(pack_b_kernel, dim3(192), dim3(256), 0, stream,
                       sc_ws, lin2_ws, sc_wv, lin2_wv, b_pre);
    hipLaunchKernelGGL(pack_w2a_kernel, dim3(16), dim3(256), 0, stream, fc_w2, w2a);
    hipLaunchKernelGGL(node_lin1, dim3(625), dim3(256), 0, stream,
                       node_feats, lin1_ws, lin1_wv, y);

    hipMemsetAsync(deg, 0, (size_t)N_NODES * sizeof(int), stream);
    hipLaunchKernelGGL(hist_kernel, dim3(625), dim3(256), 0, stream, edge_index, deg);
    hipLaunchKernelGGL(scan_kernel, dim3(1), dim3(1024), 0, stream, deg, row_start, cursor);
    hipLaunchKernelGGL(scatter_kernel, dim3(625), dim3(256), 0, stream,
                       edge_index, cursor, edge_list);
    hipLaunchKernelGGL(edge_w_mfma, dim3(2500), dim3(256), 0, stream,
                       edge_feats, fc_w0, fc_w1, w2a, w_planes);
    hipLaunchKernelGGL(gather_kernel, dim3(5000), dim3(256), 0, stream,
                       row_start, edge_list, edge_index, edge_attrs, w_planes, y, acc);

    hipLaunchKernelGGL(node_out_mfma, dim3(SBLK + VBLK), dim3(256), 0, stream,
                       node_feats, node_attrs, acc, b_pre, out);
}

// Round 6
// 513.444 us; speedup vs baseline: 1.3512x; 1.3512x over previous
//
#include <hip/hip_runtime.h>
#include <hip/hip_bf16.h>
#include <math.h>

#define N_NODES 10000
#define N_EDGES 160000
#define SBLK 157            // ceil(10000/64) s-GEMM blocks
#define VBLK 469            // ceil(30000/64) v-GEMM blocks

typedef __attribute__((ext_vector_type(8))) short short8x;
typedef __attribute__((ext_vector_type(4))) float floatx4;

union S8 { short8x v; unsigned short u[8]; uint4 q; };

__device__ __forceinline__ unsigned short f2bf(float x) {
    unsigned int u = __float_as_uint(x);
    return (unsigned short)((u + 0x7fffu + ((u >> 16) & 1u)) >> 16);
}
__device__ __forceinline__ float bf2f(unsigned short u) {
    return __uint_as_float(((unsigned)u) << 16);
}
__device__ __forceinline__ float silu_c(float x) {
    return 1.679f * x / (1.0f + __expf(-x));
}

// ---------------- Kernel A: y = lin1(node_feats), layout y[n][u][4]={s,v0,v1,v2} ----------------
__global__ __launch_bounds__(256) void node_lin1(
    const float* __restrict__ node_feats,
    const float* __restrict__ lin1_ws,
    const float* __restrict__ lin1_wv,
    float* __restrict__ y)
{
    __shared__ float xf[16 * 520];
    const int blk = blockIdx.x;      // 625
    const int t = threadIdx.x;
    const int base = blk * 16;

    const float4* nf4 = (const float4*)(node_feats + (size_t)base * 512);
    #pragma unroll
    for (int r = 0; r < 8; r++) {
        int i4 = r * 256 + t;
        int flat = i4 * 4;
        int n = flat >> 9;
        int off = flat & 511;
        *(float4*)&xf[n * 520 + off] = nf4[i4];
    }
    __syncthreads();

    const int n_loc = t >> 4;
    const int w0 = (t & 15) * 8;
    float as[8];
    float av[8][3];
    #pragma unroll
    for (int j = 0; j < 8; j++) { as[j] = 0.f; av[j][0] = 0.f; av[j][1] = 0.f; av[j][2] = 0.f; }

    const float* xrow = &xf[n_loc * 520];
    #pragma unroll 1
    for (int u = 0; u < 128; u++) {
        float xs  = xrow[u];
        float xv0 = xrow[128 + u*3 + 0];
        float xv1 = xrow[128 + u*3 + 1];
        float xv2 = xrow[128 + u*3 + 2];
        float ws[8], wvv[8];
        *(float4*)&ws[0] = *(const float4*)&lin1_ws[u*128 + w0];
        *(float4*)&ws[4] = *(const float4*)&lin1_ws[u*128 + w0 + 4];
        *(float4*)&wvv[0] = *(const float4*)&lin1_wv[u*128 + w0];
        *(float4*)&wvv[4] = *(const float4*)&lin1_wv[u*128 + w0 + 4];
        #pragma unroll
        for (int j = 0; j < 8; j++) {
            as[j]    += xs  * ws[j];
            av[j][0] += xv0 * wvv[j];
            av[j][1] += xv1 * wvv[j];
            av[j][2] += xv2 * wvv[j];
        }
    }

    const float l1 = 0.0883883476483f;  // 1/sqrt(128)
    const int node = base + n_loc;
    float* yrow = y + (size_t)node * 512;
    #pragma unroll
    for (int j = 0; j < 8; j++) {
        float4 o = make_float4(as[j] * l1, av[j][0] * l1, av[j][1] * l1, av[j][2] * l1);
        *(float4*)&yrow[(w0 + j) * 4] = o;
    }
}

// ---------------- CSR build ----------------
__global__ __launch_bounds__(256) void hist_kernel(const int* __restrict__ edge_index,
                                                   int* __restrict__ deg) {
    int e = blockIdx.x * 256 + threadIdx.x;
    if (e < N_EDGES) atomicAdd(&deg[edge_index[e]], 1);
}

__global__ __launch_bounds__(1024) void scan_kernel(const int* __restrict__ deg,
                                                    int* __restrict__ row_start,
                                                    int* __restrict__ cursor) {
    __shared__ int wsum[16];
    __shared__ int carry_s;
    const int t = threadIdx.x;        // 0..1023
    const int lane = t & 63, w = t >> 6;
    if (t == 0) carry_s = 0;
    __syncthreads();
    for (int chunk = 0; chunk < 10; chunk++) {
        int idx = chunk * 1024 + t;
        int v = (idx < N_NODES) ? deg[idx] : 0;
        int x = v;
        #pragma unroll
        for (int off = 1; off < 64; off <<= 1) {
            int yv = __shfl_up(x, off, 64);
            if (lane >= off) x += yv;
        }
        if (lane == 63) wsum[w] = x;
        __syncthreads();
        int wpre = 0;
        for (int i = 0; i < w; i++) wpre += wsum[i];
        int incl = x + wpre + carry_s;
        int excl = incl - v;
        if (idx < N_NODES) { row_start[idx] = excl; cursor[idx] = excl; }
        __syncthreads();
        if (t == 1023) carry_s = incl;
        __syncthreads();
    }
    if (t == 0) row_start[N_NODES] = carry_s;
}

__global__ __launch_bounds__(256) void scatter_kernel(const int* __restrict__ edge_index,
                                                      int* __restrict__ cursor,
                                                      int* __restrict__ edge_list) {
    int e = blockIdx.x * 256 + threadIdx.x;
    if (e < N_EDGES) {
        int pos = atomicAdd(&cursor[edge_index[e]], 1);
        edge_list[pos] = e;
    }
}

// ---------------- pack_w2a: w2/8 -> bf16, MFMA A-fragment order (A = w2^T) ----------------
__global__ __launch_bounds__(256) void pack_w2a_kernel(
    const float* __restrict__ fc_w2, unsigned short* __restrict__ w2a)
{
    int id = blockIdx.x * 256 + threadIdx.x;   // 0..4095
    int lane = id & 63;
    int mfg = (id >> 6) & 31;
    int ks = id >> 11;
    int col = mfg * 16 + (lane & 15);
    int k0 = ks * 32 + (lane >> 4) * 8;
    S8 pk;
    #pragma unroll
    for (int j = 0; j < 8; j++)
        pk.u[j] = f2bf(fc_w2[(k0 + j) * 512 + col] * 0.125f);
    *(uint4*)(w2a + (size_t)id * 8) = pk.q;
}

// ---------------- pack_w1a: w1/8 -> bf16, MFMA A-fragment order (A = w1^T) ----------------
// slot id = (ks*4 + mf)*64 + lane; value j: w1[k][m]*0.125,
// k = ks*32 + (lane>>4)*8 + j, m = mf*16 + (lane&15)
__global__ __launch_bounds__(256) void pack_w1a_kernel(
    const float* __restrict__ fc_w1, unsigned short* __restrict__ w1a)
{
    int id = blockIdx.x * 256 + threadIdx.x;   // 0..511
    int lane = id & 63;
    int mf = (id >> 6) & 3;
    int ks = id >> 8;
    int m = mf * 16 + (lane & 15);
    int k0 = ks * 32 + (lane >> 4) * 8;
    S8 pk;
    #pragma unroll
    for (int j = 0; j < 8; j++)
        pk.u[j] = f2bf(fc_w1[(k0 + j) * 64 + m] * 0.125f);
    *(uint4*)(w1a + (size_t)id * 8) = pk.q;
}

// ---------------- Kernel B1: edge MLP (phase2+3 via MFMA) -> planar bf16 w ----------------
// w_planes[comp][e][u], comp in {ss, sv, vs, vv}
__global__ __launch_bounds__(256) void edge_w_mfma(
    const float* __restrict__ edge_feats,
    const float* __restrict__ fc_w0,
    const unsigned short* __restrict__ w1a,
    const unsigned short* __restrict__ w2a,
    unsigned short* __restrict__ w_planes)
{
    // LDS: [0,36864) = union{ ef(2304) + h0b(9216)  |  T(4*64*72 ushort = 36864) }
    //      [36864, 46080) = h1b (64x72 ushort)
    __shared__ __align__(16) unsigned char smem[46080];
    float* ef = (float*)smem;                                   // 64*9 f32
    unsigned short* h0b = (unsigned short*)(smem + 2304);       // 64 x 72 bf16
    unsigned short* T   = (unsigned short*)smem;                // 4 x 64 x 72 bf16 (epilogue)
    unsigned short* h1b = (unsigned short*)(smem + 36864);      // 64 x 72 bf16

    const int blk = blockIdx.x;      // 2500
    const int t = threadIdx.x;
    const int eb0 = blk * 64;
    const int lane = t & 63;
    const int wv = t >> 6;
    const int quad = lane >> 4;
    const int m15 = lane & 15;

    // stage edge_feats (64 x 8)
    #pragma unroll
    for (int r = 0; r < 2; r++) {
        int idx = r * 256 + t;
        ef[(idx >> 3) * 9 + (idx & 7)] = edge_feats[(size_t)eb0 * 8 + idx];
    }
    __syncthreads();

    // phase 1 (VALU, f32): h0 = silu_c(ef @ w0 / sqrt(8)) -> bf16 into h0b[e][k]
    {
        const int e_loc = t >> 2;
        const int c0 = (t & 3) * 16;
        float a0[16];
        #pragma unroll
        for (int i = 0; i < 16; i++) a0[i] = 0.f;
        const float* efr = &ef[e_loc * 9];
        #pragma unroll
        for (int k = 0; k < 8; k++) {
            float ek = efr[k];
            float w[16];
            #pragma unroll
            for (int q4 = 0; q4 < 4; q4++)
                *(float4*)&w[q4*4] = *(const float4*)&fc_w0[k*64 + c0 + q4*4];
            #pragma unroll
            for (int i = 0; i < 16; i++) a0[i] += ek * w[i];
        }
        const float is8 = 0.35355339059f;  // 1/sqrt(8)
        S8 p0, p1;
        #pragma unroll
        for (int i = 0; i < 8; i++) {
            p0.u[i] = f2bf(silu_c(a0[i] * is8));
            p1.u[i] = f2bf(silu_c(a0[8 + i] * is8));
        }
        *(uint4*)&h0b[e_loc * 72 + c0]     = p0.q;
        *(uint4*)&h0b[e_loc * 72 + c0 + 8] = p1.q;
    }
    __syncthreads();

    // phase 2 (MFMA): h1 = silu_c(h0 @ w1 / 8) -> bf16 into h1b[e][col]
    // wave wv owns cols wv*16..wv*16+15 (mf = wv), all 64 edges
    {
        floatx4 c2[4];
        #pragma unroll
        for (int ee = 0; ee < 4; ee++) c2[ee] = (floatx4){0.f, 0.f, 0.f, 0.f};
        const uint4* w1aq = (const uint4*)w1a;
        #pragma unroll
        for (int ks = 0; ks < 2; ks++) {
            S8 afr;
            afr.q = w1aq[(ks*4 + wv)*64 + lane];
            #pragma unroll
            for (int ee = 0; ee < 4; ee++) {
                S8 bfr;
                bfr.q = *(const uint4*)&h0b[(ee*16 + m15) * 72 + ks*32 + quad*8];
                c2[ee] = __builtin_amdgcn_mfma_f32_16x16x32_bf16(afr.v, bfr.v, c2[ee], 0, 0, 0);
            }
        }
        // D2: lane holds (col = wv*16 + quad*4 + i, e = ee*16 + m15)
        #pragma unroll
        for (int ee = 0; ee < 4; ee++) {
            ushort4 pk = make_ushort4(f2bf(silu_c(c2[ee][0])), f2bf(silu_c(c2[ee][1])),
                                      f2bf(silu_c(c2[ee][2])), f2bf(silu_c(c2[ee][3])));
            *(ushort4*)&h1b[(ee*16 + m15) * 72 + wv*16 + quad*4] = pk;
        }
    }
    __syncthreads();

    // phase 3 (MFMA, two passes of 4 m-frags to halve live accumulators):
    // D[m=outcol(512)][n=edge]; wave wv -> comp wv; pass p -> cols p*64..p*64+63 of that comp
    const uint4* w2aq = (const uint4*)w2a;
    #pragma unroll 1
    for (int p = 0; p < 2; p++) {
        floatx4 c3[4][4];   // [mf'][ee]
        #pragma unroll
        for (int mf = 0; mf < 4; mf++)
            #pragma unroll
            for (int ee = 0; ee < 4; ee++)
                c3[mf][ee] = (floatx4){0.f, 0.f, 0.f, 0.f};

        #pragma unroll
        for (int ks = 0; ks < 2; ks++) {
            S8 bfr[4];
            #pragma unroll
            for (int ee = 0; ee < 4; ee++)
                bfr[ee].q = *(const uint4*)&h1b[(ee*16 + m15) * 72 + ks*32 + quad*8];
            #pragma unroll
            for (int mf = 0; mf < 4; mf++) {
                S8 afr;
                afr.q = w2aq[(size_t)(ks*32 + wv*8 + p*4 + mf) * 64 + lane];
                #pragma unroll
                for (int ee = 0; ee < 4; ee++)
                    c3[mf][ee] = __builtin_amdgcn_mfma_f32_16x16x32_bf16(afr.v, bfr[ee].v, c3[mf][ee], 0, 0, 0);
            }
        }

        // dump: c3[mf][ee][i] = w[col' = mf*16+quad*4+i][e = ee*16+m15] for comp wv
        #pragma unroll
        for (int mf = 0; mf < 4; mf++) {
            #pragma unroll
            for (int ee = 0; ee < 4; ee++) {
                ushort4 pk = make_ushort4(f2bf(c3[mf][ee][0]), f2bf(c3[mf][ee][1]),
                                          f2bf(c3[mf][ee][2]), f2bf(c3[mf][ee][3]));
                *(ushort4*)&T[wv*4608 + (ee*16 + m15)*72 + mf*16 + quad*4] = pk;
            }
        }
        __syncthreads();

        // coalesced store: per comp, rows of 128 contiguous bytes (fully-covered lines)
        #pragma unroll
        for (int it = 0; it < 8; it++) {
            int idx = it * 256 + t;          // 0..2047
            int comp = idx >> 9;
            int rem = idx & 511;
            int e  = rem >> 3;
            int ch = rem & 7;
            uint4 vtmp = *(const uint4*)&T[comp*4608 + e*72 + ch*8];
            unsigned short* dstp = w_planes + (size_t)comp * N_EDGES * 128
                                 + (size_t)(eb0 + e) * 128 + p*64 + ch*8;
            *(uint4*)dstp = vtmp;
        }
        __syncthreads();
    }
}

// ---------------- Kernel B2: per-node gather (no atomics, planar w) ----------------
__global__ __launch_bounds__(256) void gather_kernel(
    const int* __restrict__ row_start,
    const int* __restrict__ edge_list,
    const int* __restrict__ edge_index,
    const float* __restrict__ edge_attrs,
    const unsigned short* __restrict__ w_planes,
    const float* __restrict__ y,
    float* __restrict__ acc)
{
    const int t = threadIdx.x;
    const int half = t >> 7;
    const int u = t & 127;
    const int n = blockIdx.x * 2 + half;   // 5000 blocks
    const int sbeg = row_start[n];
    const int send = row_start[n + 1];

    float aS0 = 0.f, aS1 = 0.f;
    float aV2x = 0.f, aV2y = 0.f, aV2z = 0.f;
    float aV3x = 0.f, aV3y = 0.f, aV3z = 0.f;

    const unsigned short* pss = w_planes;
    const unsigned short* psv = w_planes + (size_t)1 * N_EDGES * 128;
    const unsigned short* pvs = w_planes + (size_t)2 * N_EDGES * 128;
    const unsigned short* pvv = w_planes + (size_t)3 * N_EDGES * 128;

    for (int i = sbeg; i < send; i++) {
        int e = edge_list[i];
        int src = edge_index[N_EDGES + e];
        size_t eo = (size_t)e * 128 + u;
        float wss = bf2f(pss[eo]);
        float wsv = bf2f(psv[eo]);
        float wvs = bf2f(pvs[eo]);
        float wvv = bf2f(pvv[eo]);
        float4 qv = *(const float4*)(y + (size_t)src * 512 + u * 4);
        float4 ea = *(const float4*)(edge_attrs + (size_t)e * 4);
        aS0 += wss * qv.x * ea.x;
        aS1 += wvv * (qv.y*ea.y + qv.z*ea.z + qv.w*ea.w);
        float tsv = wsv * qv.x;
        aV2x += tsv * ea.y; aV2y += tsv * ea.z; aV2z += tsv * ea.w;
        float tvs = wvs * ea.x;
        aV3x += tvs * qv.y; aV3y += tvs * qv.z; aV3z += tvs * qv.w;
    }

    const float inv = 0.25f;                 // 1/sqrt(16)
    const float s1c = 0.57735026919f * 0.25f;
    float* a = acc + (size_t)n * 1024;
    a[u] = aS0 * inv;
    a[128 + u] = aS1 * s1c;
    a[256 + u*3 + 0] = aV2x * inv;
    a[256 + u*3 + 1] = aV2y * inv;
    a[256 + u*3 + 2] = aV2z * inv;
    a[256 + (128 + u)*3 + 0] = aV3x * inv;
    a[256 + (128 + u)*3 + 1] = aV3y * inv;
    a[256 + (128 + u)*3 + 2] = aV3z * inv;
}

// ---------------- pack_b: B matrices -> bf16, MFMA B-fragment order ----------------
__global__ __launch_bounds__(256) void pack_b_kernel(
    const float* __restrict__ sc_ws, const float* __restrict__ lin2_ws,
    const float* __restrict__ sc_wv, const float* __restrict__ lin2_wv,
    unsigned short* __restrict__ b_pre)
{
    int id = blockIdx.x * 256 + threadIdx.x;     // 0..49151
    int mat = id / 24576;
    int slot = id - mat * 24576;
    int ks = slot >> 9;
    int rr = slot & 511;
    int lane = rr & 63;
    int quad = lane >> 4;
    int n = ((rr >> 6) << 4) + (lane & 15);
    const float* sc  = mat ? sc_wv  : sc_ws;
    const float* lin = mat ? lin2_wv : lin2_ws;
    S8 pk;
    #pragma unroll
    for (int j = 0; j < 8; j++) {
        int k = ks * 32 + quad * 8 + j;
        float w;
        if (k < 1280) {
            int u = k & 127, v = k >> 7;
            w = sc[(u * 10 + v) * 128 + n];
        } else {
            w = lin[(k - 1280) * 128 + n];
        }
        pk.u[j] = f2bf(w);
    }
    *(uint4*)(b_pre + (size_t)id * 8) = pk.q;
}

// ---------------- node_out as MFMA GEMM ----------------
__global__ __launch_bounds__(256) void node_out_mfma(
    const float* __restrict__ node_feats,
    const float* __restrict__ node_attrs,
    const float* __restrict__ acc,
    const unsigned short* __restrict__ b_pre,
    float* __restrict__ out)
{
    __shared__ short8x Al[256];     // 64 rows x 32 k, fragment-order packed (4 KB)
    const int bid = blockIdx.x;
    const int t = threadIdx.x;
    const int lane = t & 63;
    const int wv = t >> 6;
    const bool is_s = (bid < SBLK);

    const int r = t >> 2;
    const int q = t & 3;
    int node, comp, st;
    if (is_s) {
        int R = bid * 64 + r;
        node = (R < N_NODES) ? R : 0;
        comp = 0; st = 1;
    } else {
        int Rg = (bid - SBLK) * 64 + r;
        if (Rg >= 3 * N_NODES) Rg = 0;
        comp = Rg / N_NODES;
        node = Rg - comp * N_NODES;
        st = 3;
    }
    const float* px = is_s ? (node_feats + (size_t)node * 512)
                           : (node_feats + (size_t)node * 512 + 128 + comp);
    const float* pa = is_s ? (acc + (size_t)node * 1024)
                           : (acc + (size_t)node * 1024 + 256 + comp);
    const float* pattr = node_attrs + node * 10;

    const int a_slot = ((r >> 4) << 6) + (q << 4) + (r & 15);
    const uint4* bfrag_base = (const uint4*)(b_pre) + (is_s ? 0 : 24576);

    const float sc_norm = 0.02795084972f;   // 1/sqrt(1280)
    const float l2 = 0.0625f;               // 1/sqrt(256)

    floatx4 c[4][2];
    #pragma unroll
    for (int af = 0; af < 4; af++) {
        c[af][0] = (floatx4){0.f, 0.f, 0.f, 0.f};
        c[af][1] = (floatx4){0.f, 0.f, 0.f, 0.f};
    }

    for (int ks = 0; ks < 48; ks++) {
        S8 b0, b1;
        b0.q = bfrag_base[ks*512 + (wv*2+0)*64 + lane];
        b1.q = bfrag_base[ks*512 + (wv*2+1)*64 + lane];

        __syncthreads();
        {
            int k0 = ks * 32 + q * 8;
            S8 pk;
            if (k0 < 1280) {
                int u0 = k0 & 127;
                int v  = k0 >> 7;
                float att = pattr[v] * sc_norm;
                #pragma unroll
                for (int j = 0; j < 8; j++)
                    pk.u[j] = f2bf(px[(u0 + j) * st] * att);
            } else {
                int j2 = k0 - 1280;
                #pragma unroll
                for (int j = 0; j < 8; j++)
                    pk.u[j] = f2bf(pa[(j2 + j) * st] * l2);
            }
            Al[a_slot] = pk.v;
        }
        __syncthreads();

        short8x a0 = Al[lane];
        short8x a1 = Al[64 + lane];
        short8x a2 = Al[128 + lane];
        short8x a3 = Al[192 + lane];
        c[0][0] = __builtin_amdgcn_mfma_f32_16x16x32_bf16(a0, b0.v, c[0][0], 0, 0, 0);
        c[0][1] = __builtin_amdgcn_mfma_f32_16x16x32_bf16(a0, b1.v, c[0][1], 0, 0, 0);
        c[1][0] = __builtin_amdgcn_mfma_f32_16x16x32_bf16(a1, b0.v, c[1][0], 0, 0, 0);
        c[1][1] = __builtin_amdgcn_mfma_f32_16x16x32_bf16(a1, b1.v, c[1][1], 0, 0, 0);
        c[2][0] = __builtin_amdgcn_mfma_f32_16x16x32_bf16(a2, b0.v, c[2][0], 0, 0, 0);
        c[2][1] = __builtin_amdgcn_mfma_f32_16x16x32_bf16(a2, b1.v, c[2][1], 0, 0, 0);
        c[3][0] = __builtin_amdgcn_mfma_f32_16x16x32_bf16(a3, b0.v, c[3][0], 0, 0, 0);
        c[3][1] = __builtin_amdgcn_mfma_f32_16x16x32_bf16(a3, b1.v, c[3][1], 0, 0, 0);
    }

    const int m = lane & 15;
    const int rq = (lane >> 4) * 4;
    if (is_s) {
        const int n0 = bid * 64;
        #pragma unroll
        for (int af = 0; af < 4; af++) {
            #pragma unroll
            for (int i = 0; i < 4; i++) {
                int n = n0 + af*16 + rq + i;
                if (n < N_NODES) {
                    out[(size_t)n*512 + wv*32 + m]      = c[af][0][i];
                    out[(size_t)n*512 + wv*32 + 16 + m] = c[af][1][i];
                }
            }
        }
    } else {
        const int r0 = (bid - SBLK) * 64;
        #pragma unroll
        for (int af = 0; af < 4; af++) {
            #pragma unroll
            for (int i = 0; i < 4; i++) {
                int Rg = r0 + af*16 + rq + i;
                if (Rg < 3 * N_NODES) {
                    int cc = Rg / N_NODES;
                    int nn = Rg - cc * N_NODES;
                    float* po = out + (size_t)nn*512 + 128 + cc;
                    po[(wv*32 + m)*3]      = c[af][0][i];
                    po[(wv*32 + 16 + m)*3] = c[af][1][i];
                }
            }
        }
    }
}

extern "C" void kernel_launch(void* const* d_in, const int* in_sizes, int n_in,
                              void* d_out, int out_size, void* d_ws, size_t ws_size,
                              hipStream_t stream) {
    const float* node_feats = (const float*)d_in[0];
    const float* node_attrs = (const float*)d_in[1];
    const float* edge_feats = (const float*)d_in[2];
    const float* edge_attrs = (const float*)d_in[3];
    const int*   edge_index = (const int*)  d_in[4];
    const float* lin1_ws    = (const float*)d_in[5];
    const float* lin1_wv    = (const float*)d_in[6];
    const float* fc_w0      = (const float*)d_in[7];
    const float* fc_w1      = (const float*)d_in[8];
    const float* fc_w2      = (const float*)d_in[9];
    const float* lin2_ws    = (const float*)d_in[10];
    const float* lin2_wv    = (const float*)d_in[11];
    const float* sc_ws      = (const float*)d_in[12];
    const float* sc_wv      = (const float*)d_in[13];
    float* out = (float*)d_out;

    // workspace layout
    float* y   = (float*)d_ws;                        //  5,120,000 f32
    float* acc = y + (size_t)N_NODES * 512;           // 10,240,000 f32
    unsigned short* w_planes = (unsigned short*)(acc + (size_t)N_NODES * 1024); // 4*160000*128 bf16
    int* deg       = (int*)(w_planes + (size_t)4 * N_EDGES * 128);
    int* row_start = deg + 10016;
    int* cursor    = row_start + 10016;
    int* edge_list = cursor + 10016;
    unsigned short* b_pre = (unsigned short*)(edge_list + N_EDGES); // 2*24576*8 bf16
    unsigned short* w2a   = b_pre + (size_t)2 * 24576 * 8;          // 4096*8 bf16
    unsigned short* w1a   = w2a + (size_t)4096 * 8;                 // 512*8 bf16
    const size_t need = (size_t)(5120000 + 10240000) * 4 + (size_t)4 * N_EDGES * 128 * 2
                      + (size_t)(10016 * 3 + N_EDGES) * 4
                      + ((size_t)2 * 24576 * 8 + (size_t)4096 * 8 + (size_t)512 * 8) * 2;
    if (ws_size < need) return;

    hipLaunchKernelGGL(pack_b_kernel, dim3(192), dim3(256), 0, stream,
                       sc_ws, lin2_ws, sc_wv, lin2_wv, b_pre);
    hipLaunchKernelGGL(pack_w2a_kernel, dim3(16), dim3(256), 0, stream, fc_w2, w2a);
    hipLaunchKernelGGL(pack_w1a_kernel, dim3(2), dim3(256), 0, stream, fc_w1, w1a);
    hipLaunchKernelGGL(node_lin1, dim3(625), dim3(256), 0, stream,
                       node_feats, lin1_ws, lin1_wv, y);

    hipMemsetAsync(deg, 0, (size_t)N_NODES * sizeof(int), stream);
    hipLaunchKernelGGL(hist_kernel, dim3(625), dim3(256), 0, stream, edge_index, deg);
    hipLaunchKernelGGL(scan_kernel, dim3(1), dim3(1024), 0, stream, deg, row_start, cursor);
    hipLaunchKernelGGL(scatter_kernel, dim3(625), dim3(256), 0, stream,
                       edge_index, cursor, edge_list);
    hipLaunchKernelGGL(edge_w_mfma, dim3(2500), dim3(256), 0, stream,
                       edge_feats, fc_w0, w1a, w2a, w_planes);
    hipLaunchKernelGGL(gather_kernel, dim3(5000), dim3(256), 0, stream,
                       row_start, edge_list, edge_index, edge_attrs, w_planes, y, acc);

    hipLaunchKernelGGL(node_out_mfma, dim3(SBLK + VBLK), dim3(256), 0, stream,
                       node_feats, node_attrs, acc, b_pre, out);
}

// Round 7
// 416.986 us; speedup vs baseline: 1.6637x; 1.2313x over previous
//
#include <hip/hip_runtime.h>
#include <hip/hip_bf16.h>
#include <math.h>

#define N_NODES 10000
#define N_EDGES 160000
#define S_BLK 79            // ceil(10000/128) s-GEMM blocks
#define V_BLK 235           // ceil(30000/128) v-GEMM blocks

typedef __attribute__((ext_vector_type(8))) short short8x;
typedef __attribute__((ext_vector_type(4))) float floatx4;

union S8 { short8x v; unsigned short u[8]; uint4 q; };

__device__ __forceinline__ unsigned short f2bf(float x) {
    unsigned int u = __float_as_uint(x);
    return (unsigned short)((u + 0x7fffu + ((u >> 16) & 1u)) >> 16);
}
__device__ __forceinline__ float bf2f(unsigned short u) {
    return __uint_as_float(((unsigned)u) << 16);
}
__device__ __forceinline__ float silu_c(float x) {
    return 1.679f * x / (1.0f + __expf(-x));
}

// ---------------- Kernel A: y = lin1(node_feats) + xvP transpose ----------------
// y[n][u][4]={s,v0,v1,v2};  xvP[(n*3+c)][u] = node_feats[n][128+u*3+c]
__global__ __launch_bounds__(256) void node_lin1(
    const float* __restrict__ node_feats,
    const float* __restrict__ lin1_ws,
    const float* __restrict__ lin1_wv,
    float* __restrict__ y,
    float* __restrict__ xvP)
{
    __shared__ float xf[16 * 520];
    const int blk = blockIdx.x;      // 625
    const int t = threadIdx.x;
    const int base = blk * 16;

    const float4* nf4 = (const float4*)(node_feats + (size_t)base * 512);
    #pragma unroll
    for (int r = 0; r < 8; r++) {
        int i4 = r * 256 + t;
        int flat = i4 * 4;
        int n = flat >> 9;
        int off = flat & 511;
        *(float4*)&xf[n * 520 + off] = nf4[i4];
    }
    __syncthreads();

    // planar x_v transpose: 16 nodes x 3 comps x 128 u
    #pragma unroll
    for (int it = 0; it < 24; it++) {
        int idx = it * 256 + t;       // 0..6143
        int u = idx & 127;
        int rest = idx >> 7;          // 0..47
        int c = rest % 3;
        int n_loc = rest / 3;
        xvP[((size_t)(base + n_loc) * 3 + c) * 128 + u] = xf[n_loc * 520 + 128 + u*3 + c];
    }

    const int n_loc = t >> 4;
    const int w0 = (t & 15) * 8;
    float as[8];
    float av[8][3];
    #pragma unroll
    for (int j = 0; j < 8; j++) { as[j] = 0.f; av[j][0] = 0.f; av[j][1] = 0.f; av[j][2] = 0.f; }

    const float* xrow = &xf[n_loc * 520];
    #pragma unroll 1
    for (int u = 0; u < 128; u++) {
        float xs  = xrow[u];
        float xv0 = xrow[128 + u*3 + 0];
        float xv1 = xrow[128 + u*3 + 1];
        float xv2 = xrow[128 + u*3 + 2];
        float ws[8], wvv[8];
        *(float4*)&ws[0] = *(const float4*)&lin1_ws[u*128 + w0];
        *(float4*)&ws[4] = *(const float4*)&lin1_ws[u*128 + w0 + 4];
        *(float4*)&wvv[0] = *(const float4*)&lin1_wv[u*128 + w0];
        *(float4*)&wvv[4] = *(const float4*)&lin1_wv[u*128 + w0 + 4];
        #pragma unroll
        for (int j = 0; j < 8; j++) {
            as[j]    += xs  * ws[j];
            av[j][0] += xv0 * wvv[j];
            av[j][1] += xv1 * wvv[j];
            av[j][2] += xv2 * wvv[j];
        }
    }

    const float l1 = 0.0883883476483f;  // 1/sqrt(128)
    const int node = base + n_loc;
    float* yrow = y + (size_t)node * 512;
    #pragma unroll
    for (int j = 0; j < 8; j++) {
        float4 o = make_float4(as[j] * l1, av[j][0] * l1, av[j][1] * l1, av[j][2] * l1);
        *(float4*)&yrow[(w0 + j) * 4] = o;
    }
}

// ---------------- CSR build ----------------
__global__ __launch_bounds__(256) void hist_kernel(const int* __restrict__ edge_index,
                                                   int* __restrict__ deg) {
    int e = blockIdx.x * 256 + threadIdx.x;
    if (e < N_EDGES) atomicAdd(&deg[edge_index[e]], 1);
}

__global__ __launch_bounds__(1024) void scan_kernel(const int* __restrict__ deg,
                                                    int* __restrict__ row_start,
                                                    int* __restrict__ cursor) {
    __shared__ int wsum[16];
    __shared__ int carry_s;
    const int t = threadIdx.x;        // 0..1023
    const int lane = t & 63, w = t >> 6;
    if (t == 0) carry_s = 0;
    __syncthreads();
    for (int chunk = 0; chunk < 10; chunk++) {
        int idx = chunk * 1024 + t;
        int v = (idx < N_NODES) ? deg[idx] : 0;
        int x = v;
        #pragma unroll
        for (int off = 1; off < 64; off <<= 1) {
            int yv = __shfl_up(x, off, 64);
            if (lane >= off) x += yv;
        }
        if (lane == 63) wsum[w] = x;
        __syncthreads();
        int wpre = 0;
        for (int i = 0; i < w; i++) wpre += wsum[i];
        int incl = x + wpre + carry_s;
        int excl = incl - v;
        if (idx < N_NODES) { row_start[idx] = excl; cursor[idx] = excl; }
        __syncthreads();
        if (t == 1023) carry_s = incl;
        __syncthreads();
    }
    if (t == 0) row_start[N_NODES] = carry_s;
}

__global__ __launch_bounds__(256) void scatter_kernel(const int* __restrict__ edge_index,
                                                      int* __restrict__ cursor,
                                                      int* __restrict__ edge_list) {
    int e = blockIdx.x * 256 + threadIdx.x;
    if (e < N_EDGES) {
        int pos = atomicAdd(&cursor[edge_index[e]], 1);
        edge_list[pos] = e;
    }
}

// ---------------- pack_w2a: w2/8 -> bf16, MFMA A-fragment order (A = w2^T) ----------------
__global__ __launch_bounds__(256) void pack_w2a_kernel(
    const float* __restrict__ fc_w2, unsigned short* __restrict__ w2a)
{
    int id = blockIdx.x * 256 + threadIdx.x;   // 0..4095
    int lane = id & 63;
    int mfg = (id >> 6) & 31;
    int ks = id >> 11;
    int col = mfg * 16 + (lane & 15);
    int k0 = ks * 32 + (lane >> 4) * 8;
    S8 pk;
    #pragma unroll
    for (int j = 0; j < 8; j++)
        pk.u[j] = f2bf(fc_w2[(k0 + j) * 512 + col] * 0.125f);
    *(uint4*)(w2a + (size_t)id * 8) = pk.q;
}

// ---------------- pack_w1a: w1/8 -> bf16, MFMA A-fragment order (A = w1^T) ----------------
__global__ __launch_bounds__(256) void pack_w1a_kernel(
    const float* __restrict__ fc_w1, unsigned short* __restrict__ w1a)
{
    int id = blockIdx.x * 256 + threadIdx.x;   // 0..511
    int lane = id & 63;
    int mf = (id >> 6) & 3;
    int ks = id >> 8;
    int m = mf * 16 + (lane & 15);
    int k0 = ks * 32 + (lane >> 4) * 8;
    S8 pk;
    #pragma unroll
    for (int j = 0; j < 8; j++)
        pk.u[j] = f2bf(fc_w1[(k0 + j) * 64 + m] * 0.125f);
    *(uint4*)(w1a + (size_t)id * 8) = pk.q;
}

// ---------------- Kernel B1: edge MLP (phase2+3 via MFMA) -> planar bf16 w ----------------
__global__ __launch_bounds__(256) void edge_w_mfma(
    const float* __restrict__ edge_feats,
    const float* __restrict__ fc_w0,
    const unsigned short* __restrict__ w1a,
    const unsigned short* __restrict__ w2a,
    unsigned short* __restrict__ w_planes)
{
    __shared__ __align__(16) unsigned char smem[46080];
    float* ef = (float*)smem;                                   // 64*9 f32
    unsigned short* h0b = (unsigned short*)(smem + 2304);       // 64 x 72 bf16
    unsigned short* T   = (unsigned short*)smem;                // 4 x 64 x 72 bf16 (epilogue)
    unsigned short* h1b = (unsigned short*)(smem + 36864);      // 64 x 72 bf16

    const int blk = blockIdx.x;      // 2500
    const int t = threadIdx.x;
    const int eb0 = blk * 64;
    const int lane = t & 63;
    const int wv = t >> 6;
    const int quad = lane >> 4;
    const int m15 = lane & 15;

    #pragma unroll
    for (int r = 0; r < 2; r++) {
        int idx = r * 256 + t;
        ef[(idx >> 3) * 9 + (idx & 7)] = edge_feats[(size_t)eb0 * 8 + idx];
    }
    __syncthreads();

    // phase 1 (VALU, f32): h0 = silu_c(ef @ w0 / sqrt(8)) -> bf16
    {
        const int e_loc = t >> 2;
        const int c0 = (t & 3) * 16;
        float a0[16];
        #pragma unroll
        for (int i = 0; i < 16; i++) a0[i] = 0.f;
        const float* efr = &ef[e_loc * 9];
        #pragma unroll
        for (int k = 0; k < 8; k++) {
            float ek = efr[k];
            float w[16];
            #pragma unroll
            for (int q4 = 0; q4 < 4; q4++)
                *(float4*)&w[q4*4] = *(const float4*)&fc_w0[k*64 + c0 + q4*4];
            #pragma unroll
            for (int i = 0; i < 16; i++) a0[i] += ek * w[i];
        }
        const float is8 = 0.35355339059f;
        S8 p0, p1;
        #pragma unroll
        for (int i = 0; i < 8; i++) {
            p0.u[i] = f2bf(silu_c(a0[i] * is8));
            p1.u[i] = f2bf(silu_c(a0[8 + i] * is8));
        }
        *(uint4*)&h0b[e_loc * 72 + c0]     = p0.q;
        *(uint4*)&h0b[e_loc * 72 + c0 + 8] = p1.q;
    }
    __syncthreads();

    // phase 2 (MFMA): h1 = silu_c(h0 @ w1 / 8)
    {
        floatx4 c2[4];
        #pragma unroll
        for (int ee = 0; ee < 4; ee++) c2[ee] = (floatx4){0.f, 0.f, 0.f, 0.f};
        const uint4* w1aq = (const uint4*)w1a;
        #pragma unroll
        for (int ks = 0; ks < 2; ks++) {
            S8 afr;
            afr.q = w1aq[(ks*4 + wv)*64 + lane];
            #pragma unroll
            for (int ee = 0; ee < 4; ee++) {
                S8 bfr;
                bfr.q = *(const uint4*)&h0b[(ee*16 + m15) * 72 + ks*32 + quad*8];
                c2[ee] = __builtin_amdgcn_mfma_f32_16x16x32_bf16(afr.v, bfr.v, c2[ee], 0, 0, 0);
            }
        }
        #pragma unroll
        for (int ee = 0; ee < 4; ee++) {
            ushort4 pk = make_ushort4(f2bf(silu_c(c2[ee][0])), f2bf(silu_c(c2[ee][1])),
                                      f2bf(silu_c(c2[ee][2])), f2bf(silu_c(c2[ee][3])));
            *(ushort4*)&h1b[(ee*16 + m15) * 72 + wv*16 + quad*4] = pk;
        }
    }
    __syncthreads();

    // phase 3 (MFMA, two passes of 4 m-frags)
    const uint4* w2aq = (const uint4*)w2a;
    #pragma unroll 1
    for (int p = 0; p < 2; p++) {
        floatx4 c3[4][4];
        #pragma unroll
        for (int mf = 0; mf < 4; mf++)
            #pragma unroll
            for (int ee = 0; ee < 4; ee++)
                c3[mf][ee] = (floatx4){0.f, 0.f, 0.f, 0.f};

        #pragma unroll
        for (int ks = 0; ks < 2; ks++) {
            S8 bfr[4];
            #pragma unroll
            for (int ee = 0; ee < 4; ee++)
                bfr[ee].q = *(const uint4*)&h1b[(ee*16 + m15) * 72 + ks*32 + quad*8];
            #pragma unroll
            for (int mf = 0; mf < 4; mf++) {
                S8 afr;
                afr.q = w2aq[(size_t)(ks*32 + wv*8 + p*4 + mf) * 64 + lane];
                #pragma unroll
                for (int ee = 0; ee < 4; ee++)
                    c3[mf][ee] = __builtin_amdgcn_mfma_f32_16x16x32_bf16(afr.v, bfr[ee].v, c3[mf][ee], 0, 0, 0);
            }
        }

        #pragma unroll
        for (int mf = 0; mf < 4; mf++) {
            #pragma unroll
            for (int ee = 0; ee < 4; ee++) {
                ushort4 pk = make_ushort4(f2bf(c3[mf][ee][0]), f2bf(c3[mf][ee][1]),
                                          f2bf(c3[mf][ee][2]), f2bf(c3[mf][ee][3]));
                *(ushort4*)&T[wv*4608 + (ee*16 + m15)*72 + mf*16 + quad*4] = pk;
            }
        }
        __syncthreads();

        #pragma unroll
        for (int it = 0; it < 8; it++) {
            int idx = it * 256 + t;          // 0..2047
            int comp = idx >> 9;
            int rem = idx & 511;
            int e  = rem >> 3;
            int ch = rem & 7;
            uint4 vtmp = *(const uint4*)&T[comp*4608 + e*72 + ch*8];
            unsigned short* dstp = w_planes + (size_t)comp * N_EDGES * 128
                                 + (size_t)(eb0 + e) * 128 + p*64 + ch*8;
            *(uint4*)dstp = vtmp;
        }
        __syncthreads();
    }
}

// ---------------- Kernel B2: per-node gather -> planar accS/accV ----------------
__global__ __launch_bounds__(256) void gather_kernel(
    const int* __restrict__ row_start,
    const int* __restrict__ edge_list,
    const int* __restrict__ edge_index,
    const float* __restrict__ edge_attrs,
    const unsigned short* __restrict__ w_planes,
    const float* __restrict__ y,
    float* __restrict__ accS,
    float* __restrict__ accV)
{
    const int t = threadIdx.x;
    const int half = t >> 7;
    const int u = t & 127;
    const int n = blockIdx.x * 2 + half;   // 5000 blocks
    const int sbeg = row_start[n];
    const int send = row_start[n + 1];

    float aS0 = 0.f, aS1 = 0.f;
    float aV2x = 0.f, aV2y = 0.f, aV2z = 0.f;
    float aV3x = 0.f, aV3y = 0.f, aV3z = 0.f;

    const unsigned short* pss = w_planes;
    const unsigned short* psv = w_planes + (size_t)1 * N_EDGES * 128;
    const unsigned short* pvs = w_planes + (size_t)2 * N_EDGES * 128;
    const unsigned short* pvv = w_planes + (size_t)3 * N_EDGES * 128;

    for (int i = sbeg; i < send; i++) {
        int e = edge_list[i];
        int src = edge_index[N_EDGES + e];
        size_t eo = (size_t)e * 128 + u;
        float wss = bf2f(pss[eo]);
        float wsv = bf2f(psv[eo]);
        float wvs = bf2f(pvs[eo]);
        float wvv = bf2f(pvv[eo]);
        float4 qv = *(const float4*)(y + (size_t)src * 512 + u * 4);
        float4 ea = *(const float4*)(edge_attrs + (size_t)e * 4);
        aS0 += wss * qv.x * ea.x;
        aS1 += wvv * (qv.y*ea.y + qv.z*ea.z + qv.w*ea.w);
        float tsv = wsv * qv.x;
        aV2x += tsv * ea.y; aV2y += tsv * ea.z; aV2z += tsv * ea.w;
        float tvs = wvs * ea.x;
        aV3x += tvs * qv.y; aV3y += tvs * qv.z; aV3z += tvs * qv.w;
    }

    const float inv = 0.25f;                 // 1/sqrt(16)
    const float s1c = 0.57735026919f * 0.25f;
    accS[(size_t)n * 256 + u]       = aS0 * inv;
    accS[(size_t)n * 256 + 128 + u] = aS1 * s1c;
    float* av0 = accV + ((size_t)n * 3 + 0) * 256;
    float* av1 = accV + ((size_t)n * 3 + 1) * 256;
    float* av2 = accV + ((size_t)n * 3 + 2) * 256;
    av0[u] = aV2x * inv;  av0[128 + u] = aV3x * inv;
    av1[u] = aV2y * inv;  av1[128 + u] = aV3y * inv;
    av2[u] = aV2z * inv;  av2[128 + u] = aV3z * inv;
}

// ---------------- pack_b: B matrices -> bf16, MFMA B-fragment order ----------------
__global__ __launch_bounds__(256) void pack_b_kernel(
    const float* __restrict__ sc_ws, const float* __restrict__ lin2_ws,
    const float* __restrict__ sc_wv, const float* __restrict__ lin2_wv,
    unsigned short* __restrict__ b_pre)
{
    int id = blockIdx.x * 256 + threadIdx.x;     // 0..49151
    int mat = id / 24576;
    int slot = id - mat * 24576;
    int ks = slot >> 9;
    int rr = slot & 511;
    int lane = rr & 63;
    int quad = lane >> 4;
    int n = ((rr >> 6) << 4) + (lane & 15);
    const float* sc  = mat ? sc_wv  : sc_ws;
    const float* lin = mat ? lin2_wv : lin2_ws;
    S8 pk;
    #pragma unroll
    for (int j = 0; j < 8; j++) {
        int k = ks * 32 + quad * 8 + j;
        float w;
        if (k < 1280) {
            int u = k & 127, v = k >> 7;
            w = sc[(u * 10 + v) * 128 + n];
        } else {
            w = lin[(k - 1280) * 128 + n];
        }
        pk.u[j] = f2bf(w);
    }
    *(uint4*)(b_pre + (size_t)id * 8) = pk.q;
}

// ---------------- node_out as MFMA GEMM (planar A, 128-row M-tile) ----------------
__global__ __launch_bounds__(256) void node_out_mfma(
    const float* __restrict__ node_feats,
    const float* __restrict__ node_attrs,
    const float* __restrict__ xvP,
    const float* __restrict__ accS,
    const float* __restrict__ accV,
    const unsigned short* __restrict__ b_pre,
    float* __restrict__ out)
{
    __shared__ short8x Al[512];     // 128 rows x 32 k, fragment-order packed (8 KB)
    const int bid = blockIdx.x;
    const int t = threadIdx.x;
    const int lane = t & 63;
    const int wv = t >> 6;
    const bool is_s = (bid < S_BLK);

    // each thread generates 2 rows (r and r+64), k-quad q
    const int r0g = t >> 2;
    const int q = t & 3;
    const float* pxA[2];
    const float* paA[2];
    const float* patA[2];
    #pragma unroll
    for (int j = 0; j < 2; j++) {
        int r = r0g + j * 64;
        if (is_s) {
            int R = bid * 128 + r;
            int node = (R < N_NODES) ? R : 0;
            pxA[j]  = node_feats + (size_t)node * 512;
            paA[j]  = accS + (size_t)node * 256;
            patA[j] = node_attrs + node * 10;
        } else {
            int Rg = (bid - S_BLK) * 128 + r;
            if (Rg >= 3 * N_NODES) Rg = 0;
            int node = Rg / 3;
            pxA[j]  = xvP + (size_t)Rg * 128;
            paA[j]  = accV + (size_t)Rg * 256;
            patA[j] = node_attrs + node * 10;
        }
    }
    // a_slot for row r, quad q: Al[(r>>4)*64 + q*16 + (r&15)]
    int aslot[2];
    #pragma unroll
    for (int j = 0; j < 2; j++) {
        int r = r0g + j * 64;
        aslot[j] = ((r >> 4) << 6) + (q << 4) + (r & 15);
    }

    const uint4* bfrag_base = (const uint4*)(b_pre) + (is_s ? 0 : 24576);
    const float sc_norm = 0.02795084972f;   // 1/sqrt(1280)
    const float l2 = 0.0625f;               // 1/sqrt(256)

    floatx4 c[8][2];
    #pragma unroll
    for (int af = 0; af < 8; af++) {
        c[af][0] = (floatx4){0.f, 0.f, 0.f, 0.f};
        c[af][1] = (floatx4){0.f, 0.f, 0.f, 0.f};
    }

    for (int ks = 0; ks < 48; ks++) {
        S8 b0, b1;
        b0.q = bfrag_base[ks*512 + (wv*2+0)*64 + lane];
        b1.q = bfrag_base[ks*512 + (wv*2+1)*64 + lane];

        __syncthreads();
        {
            int k0 = ks * 32 + q * 8;
            #pragma unroll
            for (int j = 0; j < 2; j++) {
                S8 pk;
                if (k0 < 1280) {
                    int u0 = k0 & 127;
                    float att = patA[j][k0 >> 7] * sc_norm;
                    #pragma unroll
                    for (int i = 0; i < 8; i++)
                        pk.u[i] = f2bf(pxA[j][u0 + i] * att);
                } else {
                    int j2 = k0 - 1280;
                    #pragma unroll
                    for (int i = 0; i < 8; i++)
                        pk.u[i] = f2bf(paA[j][j2 + i] * l2);
                }
                Al[aslot[j]] = pk.v;
            }
        }
        __syncthreads();

        #pragma unroll
        for (int af = 0; af < 8; af++) {
            short8x a = Al[af*64 + lane];
            c[af][0] = __builtin_amdgcn_mfma_f32_16x16x32_bf16(a, b0.v, c[af][0], 0, 0, 0);
            c[af][1] = __builtin_amdgcn_mfma_f32_16x16x32_bf16(a, b1.v, c[af][1], 0, 0, 0);
        }
    }

    // epilogue: C/D layout col=lane&15, row=(lane>>4)*4+reg
    const int m = lane & 15;
    const int rq = (lane >> 4) * 4;
    if (is_s) {
        const int n0 = bid * 128;
        #pragma unroll
        for (int af = 0; af < 8; af++) {
            #pragma unroll
            for (int i = 0; i < 4; i++) {
                int n = n0 + af*16 + rq + i;
                if (n < N_NODES) {
                    out[(size_t)n*512 + wv*32 + m]      = c[af][0][i];
                    out[(size_t)n*512 + wv*32 + 16 + m] = c[af][1][i];
                }
            }
        }
    } else {
        const int r0 = (bid - S_BLK) * 128;
        #pragma unroll
        for (int af = 0; af < 8; af++) {
            #pragma unroll
            for (int i = 0; i < 4; i++) {
                int Rg = r0 + af*16 + rq + i;
                if (Rg < 3 * N_NODES) {
                    int nn = Rg / 3;
                    int cc = Rg - nn * 3;
                    float* po = out + (size_t)nn*512 + 128 + cc;
                    po[(wv*32 + m)*3]      = c[af][0][i];
                    po[(wv*32 + 16 + m)*3] = c[af][1][i];
                }
            }
        }
    }
}

extern "C" void kernel_launch(void* const* d_in, const int* in_sizes, int n_in,
                              void* d_out, int out_size, void* d_ws, size_t ws_size,
                              hipStream_t stream) {
    const float* node_feats = (const float*)d_in[0];
    const float* node_attrs = (const float*)d_in[1];
    const float* edge_feats = (const float*)d_in[2];
    const float* edge_attrs = (const float*)d_in[3];
    const int*   edge_index = (const int*)  d_in[4];
    const float* lin1_ws    = (const float*)d_in[5];
    const float* lin1_wv    = (const float*)d_in[6];
    const float* fc_w0      = (const float*)d_in[7];
    const float* fc_w1      = (const float*)d_in[8];
    const float* fc_w2      = (const float*)d_in[9];
    const float* lin2_ws    = (const float*)d_in[10];
    const float* lin2_wv    = (const float*)d_in[11];
    const float* sc_ws      = (const float*)d_in[12];
    const float* sc_wv      = (const float*)d_in[13];
    float* out = (float*)d_out;

    // workspace layout
    float* y    = (float*)d_ws;                          //  5,120,000 f32
    float* accS = y    + (size_t)N_NODES * 512;          //  2,560,000 f32
    float* accV = accS + (size_t)N_NODES * 256;          //  7,680,000 f32
    float* xvP  = accV + (size_t)N_NODES * 3 * 256;      //  3,840,000 f32
    unsigned short* w_planes = (unsigned short*)(xvP + (size_t)N_NODES * 3 * 128);
    int* deg       = (int*)(w_planes + (size_t)4 * N_EDGES * 128);
    int* row_start = deg + 10016;
    int* cursor    = row_start + 10016;
    int* edge_list = cursor + 10016;
    unsigned short* b_pre = (unsigned short*)(edge_list + N_EDGES); // 2*24576*8 bf16
    unsigned short* w2a   = b_pre + (size_t)2 * 24576 * 8;          // 4096*8 bf16
    unsigned short* w1a   = w2a + (size_t)4096 * 8;                 // 512*8 bf16
    const size_t need = (size_t)(5120000 + 2560000 + 7680000 + 3840000) * 4
                      + (size_t)4 * N_EDGES * 128 * 2
                      + (size_t)(10016 * 3 + N_EDGES) * 4
                      + ((size_t)2 * 24576 * 8 + (size_t)4096 * 8 + (size_t)512 * 8) * 2;
    if (ws_size < need) return;

    hipLaunchKernelGGL(pack_b_kernel, dim3(192), dim3(256), 0, stream,
                       sc_ws, lin2_ws, sc_wv, lin2_wv, b_pre);
    hipLaunchKernelGGL(pack_w2a_kernel, dim3(16), dim3(256), 0, stream, fc_w2, w2a);
    hipLaunchKernelGGL(pack_w1a_kernel, dim3(2), dim3(256), 0, stream, fc_w1, w1a);
    hipLaunchKernelGGL(node_lin1, dim3(625), dim3(256), 0, stream,
                       node_feats, lin1_ws, lin1_wv, y, xvP);

    hipMemsetAsync(deg, 0, (size_t)N_NODES * sizeof(int), stream);
    hipLaunchKernelGGL(hist_kernel, dim3(625), dim3(256), 0, stream, edge_index, deg);
    hipLaunchKernelGGL(scan_kernel, dim3(1), dim3(1024), 0, stream, deg, row_start, cursor);
    hipLaunchKernelGGL(scatter_kernel, dim3(625), dim3(256), 0, stream,
                       edge_index, cursor, edge_list);
    hipLaunchKernelGGL(edge_w_mfma, dim3(2500), dim3(256), 0, stream,
                       edge_feats, fc_w0, w1a, w2a, w_planes);
    hipLaunchKernelGGL(gather_kernel, dim3(5000), dim3(256), 0, stream,
                       row_start, edge_list, edge_index, edge_attrs, w_planes, y, accS, accV);

    hipLaunchKernelGGL(node_out_mfma, dim3(S_BLK + V_BLK), dim3(256), 0, stream,
                       node_feats, node_attrs, xvP, accS, accV, b_pre, out);
}

// Round 9
// 388.916 us; speedup vs baseline: 1.7838x; 1.0722x over previous
//
#include <hip/hip_runtime.h>
#include <hip/hip_bf16.h>
#include <math.h>

#define N_NODES 10000
#define N_EDGES 160000
#define S_BLK 79            // ceil(10000/128) s-GEMM blocks
#define V_BLK 235           // ceil(30000/128) v-GEMM blocks

typedef __attribute__((ext_vector_type(8))) short short8x;
typedef __attribute__((ext_vector_type(4))) float floatx4;
typedef __attribute__((ext_vector_type(4))) unsigned int uint4x;

union S8 { short8x v; unsigned short u[8]; uint4 q; };

__device__ __forceinline__ unsigned short f2bf(float x) {
    unsigned int u = __float_as_uint(x);
    return (unsigned short)((u + 0x7fffu + ((u >> 16) & 1u)) >> 16);
}
__device__ __forceinline__ float bf2f(unsigned short u) {
    return __uint_as_float(((unsigned)u) << 16);
}
__device__ __forceinline__ float silu_c(float x) {
    return 1.679f * x / (1.0f + __expf(-x));
}

// ---------------- Kernel A: y = lin1(node_feats) + xvP transpose ----------------
__global__ __launch_bounds__(256) void node_lin1(
    const float* __restrict__ node_feats,
    const float* __restrict__ lin1_ws,
    const float* __restrict__ lin1_wv,
    float* __restrict__ y,
    float* __restrict__ xvP)
{
    __shared__ float xf[16 * 520];
    const int blk = blockIdx.x;      // 625
    const int t = threadIdx.x;
    const int base = blk * 16;

    const float4* nf4 = (const float4*)(node_feats + (size_t)base * 512);
    #pragma unroll
    for (int r = 0; r < 8; r++) {
        int i4 = r * 256 + t;
        int flat = i4 * 4;
        int n = flat >> 9;
        int off = flat & 511;
        *(float4*)&xf[n * 520 + off] = nf4[i4];
    }
    __syncthreads();

    #pragma unroll
    for (int it = 0; it < 24; it++) {
        int idx = it * 256 + t;       // 0..6143
        int u = idx & 127;
        int rest = idx >> 7;
        int c = rest % 3;
        int n_loc = rest / 3;
        xvP[((size_t)(base + n_loc) * 3 + c) * 128 + u] = xf[n_loc * 520 + 128 + u*3 + c];
    }

    const int n_loc = t >> 4;
    const int w0 = (t & 15) * 8;
    float as[8];
    float av[8][3];
    #pragma unroll
    for (int j = 0; j < 8; j++) { as[j] = 0.f; av[j][0] = 0.f; av[j][1] = 0.f; av[j][2] = 0.f; }

    const float* xrow = &xf[n_loc * 520];
    #pragma unroll 1
    for (int u = 0; u < 128; u++) {
        float xs  = xrow[u];
        float xv0 = xrow[128 + u*3 + 0];
        float xv1 = xrow[128 + u*3 + 1];
        float xv2 = xrow[128 + u*3 + 2];
        float ws[8], wvv[8];
        *(float4*)&ws[0] = *(const float4*)&lin1_ws[u*128 + w0];
        *(float4*)&ws[4] = *(const float4*)&lin1_ws[u*128 + w0 + 4];
        *(float4*)&wvv[0] = *(const float4*)&lin1_wv[u*128 + w0];
        *(float4*)&wvv[4] = *(const float4*)&lin1_wv[u*128 + w0 + 4];
        #pragma unroll
        for (int j = 0; j < 8; j++) {
            as[j]    += xs  * ws[j];
            av[j][0] += xv0 * wvv[j];
            av[j][1] += xv1 * wvv[j];
            av[j][2] += xv2 * wvv[j];
        }
    }

    const float l1 = 0.0883883476483f;  // 1/sqrt(128)
    const int node = base + n_loc;
    float* yrow = y + (size_t)node * 512;
    #pragma unroll
    for (int j = 0; j < 8; j++) {
        float4 o = make_float4(as[j] * l1, av[j][0] * l1, av[j][1] * l1, av[j][2] * l1);
        *(float4*)&yrow[(w0 + j) * 4] = o;
    }
}

// ---------------- CSR build ----------------
__global__ __launch_bounds__(256) void hist_kernel(const int* __restrict__ edge_index,
                                                   int* __restrict__ deg) {
    int e = blockIdx.x * 256 + threadIdx.x;
    if (e < N_EDGES) atomicAdd(&deg[edge_index[e]], 1);
}

__global__ __launch_bounds__(1024) void scan_kernel(const int* __restrict__ deg,
                                                    int* __restrict__ row_start,
                                                    int* __restrict__ cursor) {
    __shared__ int wsum[16];
    __shared__ int carry_s;
    const int t = threadIdx.x;        // 0..1023
    const int lane = t & 63, w = t >> 6;
    if (t == 0) carry_s = 0;
    __syncthreads();
    for (int chunk = 0; chunk < 10; chunk++) {
        int idx = chunk * 1024 + t;
        int v = (idx < N_NODES) ? deg[idx] : 0;
        int x = v;
        #pragma unroll
        for (int off = 1; off < 64; off <<= 1) {
            int yv = __shfl_up(x, off, 64);
            if (lane >= off) x += yv;
        }
        if (lane == 63) wsum[w] = x;
        __syncthreads();
        int wpre = 0;
        for (int i = 0; i < w; i++) wpre += wsum[i];
        int incl = x + wpre + carry_s;
        int excl = incl - v;
        if (idx < N_NODES) { row_start[idx] = excl; cursor[idx] = excl; }
        __syncthreads();
        if (t == 1023) carry_s = incl;
        __syncthreads();
    }
    if (t == 0) row_start[N_NODES] = carry_s;
}

// scatter: also emit sorted src + sorted edge_attrs so gather has zero indirection
__global__ __launch_bounds__(256) void scatter_kernel(const int* __restrict__ edge_index,
                                                      const float* __restrict__ edge_attrs,
                                                      int* __restrict__ cursor,
                                                      int* __restrict__ edge_list,
                                                      int* __restrict__ srcs,
                                                      float* __restrict__ ea_sorted) {
    int e = blockIdx.x * 256 + threadIdx.x;
    if (e < N_EDGES) {
        int pos = atomicAdd(&cursor[edge_index[e]], 1);
        edge_list[pos] = e;
        srcs[pos] = edge_index[N_EDGES + e];
        float4 ea = *(const float4*)(edge_attrs + (size_t)e * 4);
        *(float4*)(ea_sorted + (size_t)pos * 4) = ea;
    }
}

// ---------------- pack_w2a: w2/8 -> bf16, MFMA A-fragment order ----------------
__global__ __launch_bounds__(256) void pack_w2a_kernel(
    const float* __restrict__ fc_w2, unsigned short* __restrict__ w2a)
{
    int id = blockIdx.x * 256 + threadIdx.x;   // 0..4095
    int lane = id & 63;
    int mfg = (id >> 6) & 31;
    int ks = id >> 11;
    int col = mfg * 16 + (lane & 15);
    int k0 = ks * 32 + (lane >> 4) * 8;
    S8 pk;
    #pragma unroll
    for (int j = 0; j < 8; j++)
        pk.u[j] = f2bf(fc_w2[(k0 + j) * 512 + col] * 0.125f);
    *(uint4*)(w2a + (size_t)id * 8) = pk.q;
}

// ---------------- pack_w1a: w1/8 -> bf16, MFMA A-fragment order ----------------
__global__ __launch_bounds__(256) void pack_w1a_kernel(
    const float* __restrict__ fc_w1, unsigned short* __restrict__ w1a)
{
    int id = blockIdx.x * 256 + threadIdx.x;   // 0..511
    int lane = id & 63;
    int mf = (id >> 6) & 3;
    int ks = id >> 8;
    int m = mf * 16 + (lane & 15);
    int k0 = ks * 32 + (lane >> 4) * 8;
    S8 pk;
    #pragma unroll
    for (int j = 0; j < 8; j++)
        pk.u[j] = f2bf(fc_w1[(k0 + j) * 64 + m] * 0.125f);
    *(uint4*)(w1a + (size_t)id * 8) = pk.q;
}

// ---------------- Kernel B1: edge MLP in SORTED order -> planar bf16 w ----------------
// block handles sorted positions [eb0, eb0+64); w_planes[comp][pos][u]
__global__ __launch_bounds__(256) void edge_w_mfma(
    const float* __restrict__ edge_feats,
    const int* __restrict__ edge_list,
    const float* __restrict__ fc_w0,
    const unsigned short* __restrict__ w1a,
    const unsigned short* __restrict__ w2a,
    unsigned short* __restrict__ w_planes)
{
    __shared__ __align__(16) unsigned char smem[46080];
    float* ef = (float*)smem;                                   // 64*9 f32
    unsigned short* h0b = (unsigned short*)(smem + 2304);       // 64 x 72 bf16
    unsigned short* T   = (unsigned short*)smem;                // 4 x 64 x 72 bf16 (epilogue)
    unsigned short* h1b = (unsigned short*)(smem + 36864);      // 64 x 72 bf16
    __shared__ int eids[64];

    const int blk = blockIdx.x;      // 2500
    const int t = threadIdx.x;
    const int eb0 = blk * 64;
    const int lane = t & 63;
    const int wv = t >> 6;
    const int quad = lane >> 4;
    const int m15 = lane & 15;

    if (t < 64) eids[t] = edge_list[eb0 + t];
    __syncthreads();

    // gather edge_feats rows for the block's sorted edges (64 x 8)
    #pragma unroll
    for (int r = 0; r < 2; r++) {
        int idx = r * 256 + t;
        int el = idx >> 3;
        int k = idx & 7;
        ef[el * 9 + k] = edge_feats[(size_t)eids[el] * 8 + k];
    }
    __syncthreads();

    // phase 1 (VALU, f32): h0 = silu_c(ef @ w0 / sqrt(8)) -> bf16
    {
        const int e_loc = t >> 2;
        const int c0 = (t & 3) * 16;
        float a0[16];
        #pragma unroll
        for (int i = 0; i < 16; i++) a0[i] = 0.f;
        const float* efr = &ef[e_loc * 9];
        #pragma unroll
        for (int k = 0; k < 8; k++) {
            float ek = efr[k];
            float w[16];
            #pragma unroll
            for (int q4 = 0; q4 < 4; q4++)
                *(float4*)&w[q4*4] = *(const float4*)&fc_w0[k*64 + c0 + q4*4];
            #pragma unroll
            for (int i = 0; i < 16; i++) a0[i] += ek * w[i];
        }
        const float is8 = 0.35355339059f;
        S8 p0, p1;
        #pragma unroll
        for (int i = 0; i < 8; i++) {
            p0.u[i] = f2bf(silu_c(a0[i] * is8));
            p1.u[i] = f2bf(silu_c(a0[8 + i] * is8));
        }
        *(uint4*)&h0b[e_loc * 72 + c0]     = p0.q;
        *(uint4*)&h0b[e_loc * 72 + c0 + 8] = p1.q;
    }
    __syncthreads();

    // phase 2 (MFMA): h1 = silu_c(h0 @ w1 / 8)
    {
        floatx4 c2[4];
        #pragma unroll
        for (int ee = 0; ee < 4; ee++) c2[ee] = (floatx4){0.f, 0.f, 0.f, 0.f};
        const uint4* w1aq = (const uint4*)w1a;
        #pragma unroll
        for (int ks = 0; ks < 2; ks++) {
            S8 afr;
            afr.q = w1aq[(ks*4 + wv)*64 + lane];
            #pragma unroll
            for (int ee = 0; ee < 4; ee++) {
                S8 bfr;
                bfr.q = *(const uint4*)&h0b[(ee*16 + m15) * 72 + ks*32 + quad*8];
                c2[ee] = __builtin_amdgcn_mfma_f32_16x16x32_bf16(afr.v, bfr.v, c2[ee], 0, 0, 0);
            }
        }
        #pragma unroll
        for (int ee = 0; ee < 4; ee++) {
            ushort4 pk = make_ushort4(f2bf(silu_c(c2[ee][0])), f2bf(silu_c(c2[ee][1])),
                                      f2bf(silu_c(c2[ee][2])), f2bf(silu_c(c2[ee][3])));
            *(ushort4*)&h1b[(ee*16 + m15) * 72 + wv*16 + quad*4] = pk;
        }
    }
    __syncthreads();

    // phase 3 (MFMA, two passes of 4 m-frags)
    const uint4* w2aq = (const uint4*)w2a;
    #pragma unroll 1
    for (int p = 0; p < 2; p++) {
        floatx4 c3[4][4];
        #pragma unroll
        for (int mf = 0; mf < 4; mf++)
            #pragma unroll
            for (int ee = 0; ee < 4; ee++)
                c3[mf][ee] = (floatx4){0.f, 0.f, 0.f, 0.f};

        #pragma unroll
        for (int ks = 0; ks < 2; ks++) {
            S8 bfr[4];
            #pragma unroll
            for (int ee = 0; ee < 4; ee++)
                bfr[ee].q = *(const uint4*)&h1b[(ee*16 + m15) * 72 + ks*32 + quad*8];
            #pragma unroll
            for (int mf = 0; mf < 4; mf++) {
                S8 afr;
                afr.q = w2aq[(size_t)(ks*32 + wv*8 + p*4 + mf) * 64 + lane];
                #pragma unroll
                for (int ee = 0; ee < 4; ee++)
                    c3[mf][ee] = __builtin_amdgcn_mfma_f32_16x16x32_bf16(afr.v, bfr[ee].v, c3[mf][ee], 0, 0, 0);
            }
        }

        #pragma unroll
        for (int mf = 0; mf < 4; mf++) {
            #pragma unroll
            for (int ee = 0; ee < 4; ee++) {
                ushort4 pk = make_ushort4(f2bf(c3[mf][ee][0]), f2bf(c3[mf][ee][1]),
                                          f2bf(c3[mf][ee][2]), f2bf(c3[mf][ee][3]));
                *(ushort4*)&T[wv*4608 + (ee*16 + m15)*72 + mf*16 + quad*4] = pk;
            }
        }
        __syncthreads();

        #pragma unroll
        for (int it = 0; it < 8; it++) {
            int idx = it * 256 + t;          // 0..2047
            int comp = idx >> 9;
            int rem = idx & 511;
            int e  = rem >> 3;
            int ch = rem & 7;
            uint4x vtmp = *(const uint4x*)&T[comp*4608 + e*72 + ch*8];
            unsigned short* dstp = w_planes + (size_t)comp * N_EDGES * 128
                                 + (size_t)(eb0 + e) * 128 + p*64 + ch*8;
            __builtin_nontemporal_store(vtmp, (uint4x*)dstp);
        }
        __syncthreads();
    }
}

// ---------------- Kernel B2: per-node gather, streaming sorted w ----------------
__global__ __launch_bounds__(256) void gather_kernel(
    const int* __restrict__ row_start,
    const int* __restrict__ srcs,
    const float* __restrict__ ea_sorted,
    const unsigned short* __restrict__ w_planes,
    const float* __restrict__ y,
    float* __restrict__ accS,
    float* __restrict__ accV)
{
    const int t = threadIdx.x;
    const int half = t >> 7;
    const int u = t & 127;
    const int n = blockIdx.x * 2 + half;   // 5000 blocks
    const int sbeg = row_start[n];
    const int send = row_start[n + 1];

    float aS0 = 0.f, aS1 = 0.f;
    float aV2x = 0.f, aV2y = 0.f, aV2z = 0.f;
    float aV3x = 0.f, aV3y = 0.f, aV3z = 0.f;

    const unsigned short* pss = w_planes;
    const unsigned short* psv = w_planes + (size_t)1 * N_EDGES * 128;
    const unsigned short* pvs = w_planes + (size_t)2 * N_EDGES * 128;
    const unsigned short* pvv = w_planes + (size_t)3 * N_EDGES * 128;

    int src_next = (sbeg < send) ? srcs[sbeg] : 0;
    for (int i = sbeg; i < send; i++) {
        int src = src_next;
        if (i + 1 < send) src_next = srcs[i + 1];
        size_t eo = (size_t)i * 128 + u;
        float wss = bf2f(__builtin_nontemporal_load(&pss[eo]));
        float wsv = bf2f(__builtin_nontemporal_load(&psv[eo]));
        float wvs = bf2f(__builtin_nontemporal_load(&pvs[eo]));
        float wvv = bf2f(__builtin_nontemporal_load(&pvv[eo]));
        float4 qv = *(const float4*)(y + (size_t)src * 512 + u * 4);
        float4 ea = *(const float4*)(ea_sorted + (size_t)i * 4);
        aS0 += wss * qv.x * ea.x;
        aS1 += wvv * (qv.y*ea.y + qv.z*ea.z + qv.w*ea.w);
        float tsv = wsv * qv.x;
        aV2x += tsv * ea.y; aV2y += tsv * ea.z; aV2z += tsv * ea.w;
        float tvs = wvs * ea.x;
        aV3x += tvs * qv.y; aV3y += tvs * qv.z; aV3z += tvs * qv.w;
    }

    const float inv = 0.25f;                 // 1/sqrt(16)
    const float s1c = 0.57735026919f * 0.25f;
    accS[(size_t)n * 256 + u]       = aS0 * inv;
    accS[(size_t)n * 256 + 128 + u] = aS1 * s1c;
    float* av0 = accV + ((size_t)n * 3 + 0) * 256;
    float* av1 = accV + ((size_t)n * 3 + 1) * 256;
    float* av2 = accV + ((size_t)n * 3 + 2) * 256;
    av0[u] = aV2x * inv;  av0[128 + u] = aV3x * inv;
    av1[u] = aV2y * inv;  av1[128 + u] = aV3y * inv;
    av2[u] = aV2z * inv;  av2[128 + u] = aV3z * inv;
}

// ---------------- pack_b: B matrices -> bf16, MFMA B-fragment order ----------------
__global__ __launch_bounds__(256) void pack_b_kernel(
    const float* __restrict__ sc_ws, const float* __restrict__ lin2_ws,
    const float* __restrict__ sc_wv, const float* __restrict__ lin2_wv,
    unsigned short* __restrict__ b_pre)
{
    int id = blockIdx.x * 256 + threadIdx.x;     // 0..49151
    int mat = id / 24576;
    int slot = id - mat * 24576;
    int ks = slot >> 9;
    int rr = slot & 511;
    int lane = rr & 63;
    int quad = lane >> 4;
    int n = ((rr >> 6) << 4) + (lane & 15);
    const float* sc  = mat ? sc_wv  : sc_ws;
    const float* lin = mat ? lin2_wv : lin2_ws;
    S8 pk;
    #pragma unroll
    for (int j = 0; j < 8; j++) {
        int k = ks * 32 + quad * 8 + j;
        float w;
        if (k < 1280) {
            int u = k & 127, v = k >> 7;
            w = sc[(u * 10 + v) * 128 + n];
        } else {
            w = lin[(k - 1280) * 128 + n];
        }
        pk.u[j] = f2bf(w);
    }
    *(uint4*)(b_pre + (size_t)id * 8) = pk.q;
}

// ---------------- node_out as MFMA GEMM (planar A, 128-row M-tile) ----------------
__global__ __launch_bounds__(256) void node_out_mfma(
    const float* __restrict__ node_feats,
    const float* __restrict__ node_attrs,
    const float* __restrict__ xvP,
    const float* __restrict__ accS,
    const float* __restrict__ accV,
    const unsigned short* __restrict__ b_pre,
    float* __restrict__ out)
{
    __shared__ short8x Al[512];     // 128 rows x 32 k (8 KB)
    const int bid = blockIdx.x;
    const int t = threadIdx.x;
    const int lane = t & 63;
    const int wv = t >> 6;
    const bool is_s = (bid < S_BLK);

    const int r0g = t >> 2;
    const int q = t & 3;
    const float* pxA[2];
    const float* paA[2];
    const float* patA[2];
    #pragma unroll
    for (int j = 0; j < 2; j++) {
        int r = r0g + j * 64;
        if (is_s) {
            int R = bid * 128 + r;
            int node = (R < N_NODES) ? R : 0;
            pxA[j]  = node_feats + (size_t)node * 512;
            paA[j]  = accS + (size_t)node * 256;
            patA[j] = node_attrs + node * 10;
        } else {
            int Rg = (bid - S_BLK) * 128 + r;
            if (Rg >= 3 * N_NODES) Rg = 0;
            int node = Rg / 3;
            pxA[j]  = xvP + (size_t)Rg * 128;
            paA[j]  = accV + (size_t)Rg * 256;
            patA[j] = node_attrs + node * 10;
        }
    }
    int aslot[2];
    #pragma unroll
    for (int j = 0; j < 2; j++) {
        int r = r0g + j * 64;
        aslot[j] = ((r >> 4) << 6) + (q << 4) + (r & 15);
    }

    const uint4* bfrag_base = (const uint4*)(b_pre) + (is_s ? 0 : 24576);
    const float sc_norm = 0.02795084972f;   // 1/sqrt(1280)
    const float l2 = 0.0625f;               // 1/sqrt(256)

    floatx4 c[8][2];
    #pragma unroll
    for (int af = 0; af < 8; af++) {
        c[af][0] = (floatx4){0.f, 0.f, 0.f, 0.f};
        c[af][1] = (floatx4){0.f, 0.f, 0.f, 0.f};
    }

    for (int ks = 0; ks < 48; ks++) {
        S8 b0, b1;
        b0.q = bfrag_base[ks*512 + (wv*2+0)*64 + lane];
        b1.q = bfrag_base[ks*512 + (wv*2+1)*64 + lane];

        __syncthreads();
        {
            int k0 = ks * 32 + q * 8;
            #pragma unroll
            for (int j = 0; j < 2; j++) {
                S8 pk;
                if (k0 < 1280) {
                    int u0 = k0 & 127;
                    float att = patA[j][k0 >> 7] * sc_norm;
                    #pragma unroll
                    for (int i = 0; i < 8; i++)
                        pk.u[i] = f2bf(pxA[j][u0 + i] * att);
                } else {
                    int j2 = k0 - 1280;
                    #pragma unroll
                    for (int i = 0; i < 8; i++)
                        pk.u[i] = f2bf(paA[j][j2 + i] * l2);
                }
                Al[aslot[j]] = pk.v;
            }
        }
        __syncthreads();

        #pragma unroll
        for (int af = 0; af < 8; af++) {
            short8x a = Al[af*64 + lane];
            c[af][0] = __builtin_amdgcn_mfma_f32_16x16x32_bf16(a, b0.v, c[af][0], 0, 0, 0);
            c[af][1] = __builtin_amdgcn_mfma_f32_16x16x32_bf16(a, b1.v, c[af][1], 0, 0, 0);
        }
    }

    const int m = lane & 15;
    const int rq = (lane >> 4) * 4;
    if (is_s) {
        const int n0 = bid * 128;
        #pragma unroll
        for (int af = 0; af < 8; af++) {
            #pragma unroll
            for (int i = 0; i < 4; i++) {
                int n = n0 + af*16 + rq + i;
                if (n < N_NODES) {
                    out[(size_t)n*512 + wv*32 + m]      = c[af][0][i];
                    out[(size_t)n*512 + wv*32 + 16 + m] = c[af][1][i];
                }
            }
        }
    } else {
        const int r0 = (bid - S_BLK) * 128;
        #pragma unroll
        for (int af = 0; af < 8; af++) {
            #pragma unroll
            for (int i = 0; i < 4; i++) {
                int Rg = r0 + af*16 + rq + i;
                if (Rg < 3 * N_NODES) {
                    int nn = Rg / 3;
                    int cc = Rg - nn * 3;
                    float* po = out + (size_t)nn*512 + 128 + cc;
                    po[(wv*32 + m)*3]      = c[af][0][i];
                    po[(wv*32 + 16 + m)*3] = c[af][1][i];
                }
            }
        }
    }
}

extern "C" void kernel_launch(void* const* d_in, const int* in_sizes, int n_in,
                              void* d_out, int out_size, void* d_ws, size_t ws_size,
                              hipStream_t stream) {
    const float* node_feats = (const float*)d_in[0];
    const float* node_attrs = (const float*)d_in[1];
    const float* edge_feats = (const float*)d_in[2];
    const float* edge_attrs = (const float*)d_in[3];
    const int*   edge_index = (const int*)  d_in[4];
    const float* lin1_ws    = (const float*)d_in[5];
    const float* lin1_wv    = (const float*)d_in[6];
    const float* fc_w0      = (const float*)d_in[7];
    const float* fc_w1      = (const float*)d_in[8];
    const float* fc_w2      = (const float*)d_in[9];
    const float* lin2_ws    = (const float*)d_in[10];
    const float* lin2_wv    = (const float*)d_in[11];
    const float* sc_ws      = (const float*)d_in[12];
    const float* sc_wv      = (const float*)d_in[13];
    float* out = (float*)d_out;

    // workspace layout
    float* y    = (float*)d_ws;                          //  5,120,000 f32
    float* accS = y    + (size_t)N_NODES * 512;          //  2,560,000 f32
    float* accV = accS + (size_t)N_NODES * 256;          //  7,680,000 f32
    float* xvP  = accV + (size_t)N_NODES * 3 * 256;      //  3,840,000 f32
    unsigned short* w_planes = (unsigned short*)(xvP + (size_t)N_NODES * 3 * 128);
    int* deg       = (int*)(w_planes + (size_t)4 * N_EDGES * 128);
    int* row_start = deg + 10016;
    int* cursor    = row_start + 10016;
    int* edge_list = cursor + 10016;
    int* srcs      = edge_list + N_EDGES;
    float* ea_sorted = (float*)(srcs + N_EDGES);
    unsigned short* b_pre = (unsigned short*)(ea_sorted + (size_t)N_EDGES * 4);
    unsigned short* w2a   = b_pre + (size_t)2 * 24576 * 8;
    unsigned short* w1a   = w2a + (size_t)4096 * 8;
    const size_t need = (size_t)(5120000 + 2560000 + 7680000 + 3840000) * 4
                      + (size_t)4 * N_EDGES * 128 * 2
                      + (size_t)(10016 * 3 + N_EDGES * 2) * 4
                      + (size_t)N_EDGES * 4 * 4
                      + ((size_t)2 * 24576 * 8 + (size_t)4096 * 8 + (size_t)512 * 8) * 2;
    if (ws_size < need) return;

    hipLaunchKernelGGL(pack_b_kernel, dim3(192), dim3(256), 0, stream,
                       sc_ws, lin2_ws, sc_wv, lin2_wv, b_pre);
    hipLaunchKernelGGL(pack_w2a_kernel, dim3(16), dim3(256), 0, stream, fc_w2, w2a);
    hipLaunchKernelGGL(pack_w1a_kernel, dim3(2), dim3(256), 0, stream, fc_w1, w1a);
    hipLaunchKernelGGL(node_lin1, dim3(625), dim3(256), 0, stream,
                       node_feats, lin1_ws, lin1_wv, y, xvP);

    hipMemsetAsync(deg, 0, (size_t)N_NODES * sizeof(int), stream);
    hipLaunchKernelGGL(hist_kernel, dim3(625), dim3(256), 0, stream, edge_index, deg);
    hipLaunchKernelGGL(scan_kernel, dim3(1), dim3(1024), 0, stream, deg, row_start, cursor);
    hipLaunchKernelGGL(scatter_kernel, dim3(625), dim3(256), 0, stream,
                       edge_index, edge_attrs, cursor, edge_list, srcs, ea_sorted);
    hipLaunchKernelGGL(edge_w_mfma, dim3(2500), dim3(256), 0, stream,
                       edge_feats, edge_list, fc_w0, w1a, w2a, w_planes);
    hipLaunchKernelGGL(gather_kernel, dim3(5000), dim3(256), 0, stream,
                       row_start, srcs, ea_sorted, w_planes, y, accS, accV);

    hipLaunchKernelGGL(node_out_mfma, dim3(S_BLK + V_BLK), dim3(256), 0, stream,
                       node_feats, node_attrs, xvP, accS, accV, b_pre, out);
}

// Round 10
// 346.745 us; speedup vs baseline: 2.0007x; 1.1216x over previous
//
#include <hip/hip_runtime.h>
#include <hip/hip_bf16.h>
#include <math.h>

#define N_NODES 10000
#define N_EDGES 160000
#define S_BLK 79            // ceil(10000/128) s-GEMM blocks
#define V_BLK 235           // ceil(30000/128) v-GEMM blocks

typedef __attribute__((ext_vector_type(8))) short short8x;
typedef __attribute__((ext_vector_type(4))) float floatx4;
typedef __attribute__((ext_vector_type(4))) unsigned int uint4x;
typedef __attribute__((ext_vector_type(2))) unsigned int uint2x;

union S8 { short8x v; unsigned short u[8]; uint4 q; };
union U2 { uint2x v; unsigned short us[4]; };

__device__ __forceinline__ unsigned short f2bf(float x) {
    unsigned int u = __float_as_uint(x);
    return (unsigned short)((u + 0x7fffu + ((u >> 16) & 1u)) >> 16);
}
__device__ __forceinline__ float bf2f(unsigned short u) {
    return __uint_as_float(((unsigned)u) << 16);
}
__device__ __forceinline__ float silu_c(float x) {
    return 1.679f * x / (1.0f + __expf(-x));
}

// ---------------- pack_lin1b: lin1 weights -> bf16 B-fragment order, l1 folded ----------------
__global__ __launch_bounds__(256) void pack_lin1b_kernel(
    const float* __restrict__ lin1_ws, const float* __restrict__ lin1_wv,
    unsigned short* __restrict__ b_lin)
{
    int id = blockIdx.x * 256 + threadIdx.x;   // 0..4095
    int mat = id >> 11;
    int slot = id & 2047;
    int ks = slot >> 9;
    int rr = slot & 511;
    int nf = rr >> 6;
    int lane = rr & 63;
    int n = nf * 16 + (lane & 15);
    int k0 = ks * 32 + (lane >> 4) * 8;
    const float* w = mat ? lin1_wv : lin1_ws;
    const float l1 = 0.0883883476483f;  // 1/sqrt(128)
    S8 pk;
    #pragma unroll
    for (int j = 0; j < 8; j++)
        pk.u[j] = f2bf(w[(k0 + j) * 128 + n] * l1);
    *(uint4*)(b_lin + (size_t)id * 8) = pk.q;
}

// ---------------- Kernel A: lin1 via MFMA -> packed bf16 y + bf16 xvP ----------------
// y_pk[n][u][4] = bf16{s,v0,v1,v2};  xvP16[(n*3+c)][u] = bf16(x_v)
__global__ __launch_bounds__(256) void node_lin1_mfma(
    const float* __restrict__ node_feats,
    const unsigned short* __restrict__ b_lin,
    unsigned short* __restrict__ y_pk,
    unsigned short* __restrict__ xvP16)
{
    __shared__ __align__(16) unsigned char smem[32768];
    short8x* Al = (short8x*)smem;                 // 2048 slots (A-frags, 32 KB)
    unsigned short* Yt = (unsigned short*)smem;   // 32x128x4 ushorts (epilogue)

    const int blk = blockIdx.x;   // 313
    const int t = threadIdx.x;
    const int base = blk * 32;
    const int lane = t & 63;
    const int wv = t >> 6;
    const int m15 = lane & 15;
    const int k0q = (lane >> 4) * 8;

    // A-gen: rows = comp*32+nloc (128 rows), cols k=u (128). also emit xvP16.
    #pragma unroll
    for (int it = 0; it < 8; it++) {
        int g = wv * 8 + it;           // (af,ks) group
        int af = g >> 2;
        int ks = g & 3;
        int m = af * 16 + m15;
        int comp = m >> 5;
        int nloc = m & 31;
        int node = base + nloc;
        int valid = (node < N_NODES);
        if (!valid) node = N_NODES - 1;
        int k0 = ks * 32 + k0q;
        const float* row = node_feats + (size_t)node * 512;
        S8 pk;
        if (comp == 0) {
            float4 a = *(const float4*)&row[k0];
            float4 b = *(const float4*)&row[k0 + 4];
            pk.u[0] = f2bf(a.x); pk.u[1] = f2bf(a.y); pk.u[2] = f2bf(a.z); pk.u[3] = f2bf(a.w);
            pk.u[4] = f2bf(b.x); pk.u[5] = f2bf(b.y); pk.u[6] = f2bf(b.z); pk.u[7] = f2bf(b.w);
        } else {
            int c = comp - 1;
            #pragma unroll
            for (int j = 0; j < 8; j++)
                pk.u[j] = f2bf(row[128 + (k0 + j) * 3 + c]);
            if (valid)
                *(uint4*)&xvP16[((size_t)node * 3 + c) * 128 + k0] = pk.q;
        }
        Al[(ks * 8 + af) * 64 + lane] = pk.v;
    }
    __syncthreads();

    floatx4 c[8][2];
    #pragma unroll
    for (int af = 0; af < 8; af++) {
        c[af][0] = (floatx4){0.f, 0.f, 0.f, 0.f};
        c[af][1] = (floatx4){0.f, 0.f, 0.f, 0.f};
    }

    const uint4* bq = (const uint4*)b_lin;
    #pragma unroll
    for (int ks = 0; ks < 4; ks++) {
        S8 bs0, bs1, bv0, bv1;
        bs0.q = bq[          ks*512 + (wv*2+0)*64 + lane];
        bs1.q = bq[          ks*512 + (wv*2+1)*64 + lane];
        bv0.q = bq[2048 +    ks*512 + (wv*2+0)*64 + lane];
        bv1.q = bq[2048 +    ks*512 + (wv*2+1)*64 + lane];
        #pragma unroll
        for (int af = 0; af < 8; af++) {
            short8x a = Al[(ks*8 + af)*64 + lane];
            if (af < 2) {
                c[af][0] = __builtin_amdgcn_mfma_f32_16x16x32_bf16(a, bs0.v, c[af][0], 0, 0, 0);
                c[af][1] = __builtin_amdgcn_mfma_f32_16x16x32_bf16(a, bs1.v, c[af][1], 0, 0, 0);
            } else {
                c[af][0] = __builtin_amdgcn_mfma_f32_16x16x32_bf16(a, bv0.v, c[af][0], 0, 0, 0);
                c[af][1] = __builtin_amdgcn_mfma_f32_16x16x32_bf16(a, bv1.v, c[af][1], 0, 0, 0);
            }
        }
    }
    __syncthreads();

    // epilogue: stage packed y tile (comp interleaved), then coalesced store
    {
        const int rq = (lane >> 4) * 4;
        #pragma unroll
        for (int af = 0; af < 8; af++) {
            #pragma unroll
            for (int nf = 0; nf < 2; nf++) {
                int u = wv * 32 + nf * 16 + m15;
                #pragma unroll
                for (int i = 0; i < 4; i++) {
                    int m = af * 16 + rq + i;
                    int comp = m >> 5, nloc = m & 31;
                    Yt[(nloc * 128 + u) * 4 + comp] = f2bf(c[af][nf][i]);
                }
            }
        }
    }
    __syncthreads();
    {
        unsigned short* dst = y_pk + (size_t)base * 512;
        int nrem = N_NODES - base;
        #pragma unroll
        for (int it = 0; it < 8; it++) {
            int idx = it * 256 + t;          // uint4 index; 64 per node
            if ((idx >> 6) < nrem)
                *(uint4*)(dst + (size_t)idx * 8) = *(const uint4*)&Yt[idx * 8];
        }
    }
}

// ---------------- CSR build ----------------
__global__ __launch_bounds__(256) void hist_kernel(const int* __restrict__ edge_index,
                                                   int* __restrict__ deg) {
    int e = blockIdx.x * 256 + threadIdx.x;
    if (e < N_EDGES) atomicAdd(&deg[edge_index[e]], 1);
}

__global__ __launch_bounds__(1024) void scan_kernel(const int* __restrict__ deg,
                                                    int* __restrict__ row_start,
                                                    int* __restrict__ cursor) {
    __shared__ int wsum[16];
    __shared__ int carry_s;
    const int t = threadIdx.x;        // 0..1023
    const int lane = t & 63, w = t >> 6;
    if (t == 0) carry_s = 0;
    __syncthreads();
    for (int chunk = 0; chunk < 10; chunk++) {
        int idx = chunk * 1024 + t;
        int v = (idx < N_NODES) ? deg[idx] : 0;
        int x = v;
        #pragma unroll
        for (int off = 1; off < 64; off <<= 1) {
            int yv = __shfl_up(x, off, 64);
            if (lane >= off) x += yv;
        }
        if (lane == 63) wsum[w] = x;
        __syncthreads();
        int wpre = 0;
        for (int i = 0; i < w; i++) wpre += wsum[i];
        int incl = x + wpre + carry_s;
        int excl = incl - v;
        if (idx < N_NODES) { row_start[idx] = excl; cursor[idx] = excl; }
        __syncthreads();
        if (t == 1023) carry_s = incl;
        __syncthreads();
    }
    if (t == 0) row_start[N_NODES] = carry_s;
}

__global__ __launch_bounds__(256) void scatter_kernel(const int* __restrict__ edge_index,
                                                      const float* __restrict__ edge_attrs,
                                                      int* __restrict__ cursor,
                                                      int* __restrict__ edge_list,
                                                      int* __restrict__ srcs,
                                                      float* __restrict__ ea_sorted) {
    int e = blockIdx.x * 256 + threadIdx.x;
    if (e < N_EDGES) {
        int pos = atomicAdd(&cursor[edge_index[e]], 1);
        edge_list[pos] = e;
        srcs[pos] = edge_index[N_EDGES + e];
        float4 ea = *(const float4*)(edge_attrs + (size_t)e * 4);
        *(float4*)(ea_sorted + (size_t)pos * 4) = ea;
    }
}

// ---------------- pack_w2a: w2/8 -> bf16, MFMA A-fragment order ----------------
__global__ __launch_bounds__(256) void pack_w2a_kernel(
    const float* __restrict__ fc_w2, unsigned short* __restrict__ w2a)
{
    int id = blockIdx.x * 256 + threadIdx.x;   // 0..4095
    int lane = id & 63;
    int mfg = (id >> 6) & 31;
    int ks = id >> 11;
    int col = mfg * 16 + (lane & 15);
    int k0 = ks * 32 + (lane >> 4) * 8;
    S8 pk;
    #pragma unroll
    for (int j = 0; j < 8; j++)
        pk.u[j] = f2bf(fc_w2[(k0 + j) * 512 + col] * 0.125f);
    *(uint4*)(w2a + (size_t)id * 8) = pk.q;
}

// ---------------- pack_w1a: w1/8 -> bf16, MFMA A-fragment order ----------------
__global__ __launch_bounds__(256) void pack_w1a_kernel(
    const float* __restrict__ fc_w1, unsigned short* __restrict__ w1a)
{
    int id = blockIdx.x * 256 + threadIdx.x;   // 0..511
    int lane = id & 63;
    int mf = (id >> 6) & 3;
    int ks = id >> 8;
    int m = mf * 16 + (lane & 15);
    int k0 = ks * 32 + (lane >> 4) * 8;
    S8 pk;
    #pragma unroll
    for (int j = 0; j < 8; j++)
        pk.u[j] = f2bf(fc_w1[(k0 + j) * 64 + m] * 0.125f);
    *(uint4*)(w1a + (size_t)id * 8) = pk.q;
}

// ---------------- Kernel B1: edge MLP (sorted order) -> packed bf16 w ----------------
// w_pk[pos][u][4] = bf16{ss, sv, vs, vv}
__global__ __launch_bounds__(256) void edge_w_mfma(
    const float* __restrict__ edge_feats,
    const int* __restrict__ edge_list,
    const float* __restrict__ fc_w0,
    const unsigned short* __restrict__ w1a,
    const unsigned short* __restrict__ w2a,
    unsigned short* __restrict__ w_pk)
{
    __shared__ __align__(16) unsigned char smem[46080];
    float* ef = (float*)smem;                                   // 64*9 f32
    unsigned short* h0b = (unsigned short*)(smem + 2304);       // 64 x 72 bf16
    unsigned short* T   = (unsigned short*)smem;                // 4 x 64 x 72 bf16 (epilogue)
    unsigned short* h1b = (unsigned short*)(smem + 36864);      // 64 x 72 bf16
    __shared__ int eids[64];

    const int blk = blockIdx.x;      // 2500
    const int t = threadIdx.x;
    const int eb0 = blk * 64;
    const int lane = t & 63;
    const int wv = t >> 6;
    const int quad = lane >> 4;
    const int m15 = lane & 15;

    if (t < 64) eids[t] = edge_list[eb0 + t];
    __syncthreads();

    #pragma unroll
    for (int r = 0; r < 2; r++) {
        int idx = r * 256 + t;
        int el = idx >> 3;
        int k = idx & 7;
        ef[el * 9 + k] = edge_feats[(size_t)eids[el] * 8 + k];
    }
    __syncthreads();

    // phase 1 (VALU, f32): h0 = silu_c(ef @ w0 / sqrt(8)) -> bf16
    {
        const int e_loc = t >> 2;
        const int c0 = (t & 3) * 16;
        float a0[16];
        #pragma unroll
        for (int i = 0; i < 16; i++) a0[i] = 0.f;
        const float* efr = &ef[e_loc * 9];
        #pragma unroll
        for (int k = 0; k < 8; k++) {
            float ek = efr[k];
            float w[16];
            #pragma unroll
            for (int q4 = 0; q4 < 4; q4++)
                *(float4*)&w[q4*4] = *(const float4*)&fc_w0[k*64 + c0 + q4*4];
            #pragma unroll
            for (int i = 0; i < 16; i++) a0[i] += ek * w[i];
        }
        const float is8 = 0.35355339059f;
        S8 p0, p1;
        #pragma unroll
        for (int i = 0; i < 8; i++) {
            p0.u[i] = f2bf(silu_c(a0[i] * is8));
            p1.u[i] = f2bf(silu_c(a0[8 + i] * is8));
        }
        *(uint4*)&h0b[e_loc * 72 + c0]     = p0.q;
        *(uint4*)&h0b[e_loc * 72 + c0 + 8] = p1.q;
    }
    __syncthreads();

    // phase 2 (MFMA): h1 = silu_c(h0 @ w1 / 8)
    {
        floatx4 c2[4];
        #pragma unroll
        for (int ee = 0; ee < 4; ee++) c2[ee] = (floatx4){0.f, 0.f, 0.f, 0.f};
        const uint4* w1aq = (const uint4*)w1a;
        #pragma unroll
        for (int ks = 0; ks < 2; ks++) {
            S8 afr;
            afr.q = w1aq[(ks*4 + wv)*64 + lane];
            #pragma unroll
            for (int ee = 0; ee < 4; ee++) {
                S8 bfr;
                bfr.q = *(const uint4*)&h0b[(ee*16 + m15) * 72 + ks*32 + quad*8];
                c2[ee] = __builtin_amdgcn_mfma_f32_16x16x32_bf16(afr.v, bfr.v, c2[ee], 0, 0, 0);
            }
        }
        #pragma unroll
        for (int ee = 0; ee < 4; ee++) {
            ushort4 pk = make_ushort4(f2bf(silu_c(c2[ee][0])), f2bf(silu_c(c2[ee][1])),
                                      f2bf(silu_c(c2[ee][2])), f2bf(silu_c(c2[ee][3])));
            *(ushort4*)&h1b[(ee*16 + m15) * 72 + wv*16 + quad*4] = pk;
        }
    }
    __syncthreads();

    // phase 3 (MFMA, two passes of 4 m-frags)
    const uint4* w2aq = (const uint4*)w2a;
    #pragma unroll 1
    for (int p = 0; p < 2; p++) {
        floatx4 c3[4][4];
        #pragma unroll
        for (int mf = 0; mf < 4; mf++)
            #pragma unroll
            for (int ee = 0; ee < 4; ee++)
                c3[mf][ee] = (floatx4){0.f, 0.f, 0.f, 0.f};

        #pragma unroll
        for (int ks = 0; ks < 2; ks++) {
            S8 bfr[4];
            #pragma unroll
            for (int ee = 0; ee < 4; ee++)
                bfr[ee].q = *(const uint4*)&h1b[(ee*16 + m15) * 72 + ks*32 + quad*8];
            #pragma unroll
            for (int mf = 0; mf < 4; mf++) {
                S8 afr;
                afr.q = w2aq[(size_t)(ks*32 + wv*8 + p*4 + mf) * 64 + lane];
                #pragma unroll
                for (int ee = 0; ee < 4; ee++)
                    c3[mf][ee] = __builtin_amdgcn_mfma_f32_16x16x32_bf16(afr.v, bfr[ee].v, c3[mf][ee], 0, 0, 0);
            }
        }

        // dump comp tile to LDS: T[comp][e][col'] (col' in [0,64))
        #pragma unroll
        for (int mf = 0; mf < 4; mf++) {
            #pragma unroll
            for (int ee = 0; ee < 4; ee++) {
                ushort4 pk = make_ushort4(f2bf(c3[mf][ee][0]), f2bf(c3[mf][ee][1]),
                                          f2bf(c3[mf][ee][2]), f2bf(c3[mf][ee][3]));
                *(ushort4*)&T[wv*4608 + (ee*16 + m15)*72 + mf*16 + quad*4] = pk;
            }
        }
        __syncthreads();

        // interleave comps -> ushort4 per (e, u), contiguous 512 B/wave stores
        #pragma unroll
        for (int it = 0; it < 16; it++) {
            int idx = it * 256 + t;          // 0..4095 : (e, cu)
            int e  = idx >> 6;
            int cu = idx & 63;
            U2 pk2;
            pk2.us[0] = T[0*4608 + e*72 + cu];
            pk2.us[1] = T[1*4608 + e*72 + cu];
            pk2.us[2] = T[2*4608 + e*72 + cu];
            pk2.us[3] = T[3*4608 + e*72 + cu];
            unsigned short* dstp = w_pk + ((size_t)(eb0 + e) * 128 + p*64 + cu) * 4;
            __builtin_nontemporal_store(pk2.v, (uint2x*)dstp);
        }
        __syncthreads();
    }
}

// ---------------- Kernel B2: per-node gather, streaming sorted packed w ----------------
__global__ __launch_bounds__(256) void gather_kernel(
    const int* __restrict__ row_start,
    const int* __restrict__ srcs,
    const float* __restrict__ ea_sorted,
    const unsigned short* __restrict__ w_pk,
    const unsigned short* __restrict__ y_pk,
    float* __restrict__ accS,
    float* __restrict__ accV)
{
    const int t = threadIdx.x;
    const int half = t >> 7;
    const int u = t & 127;
    const int n = blockIdx.x * 2 + half;   // 5000 blocks
    const int sbeg = row_start[n];
    const int send = row_start[n + 1];

    float aS0 = 0.f, aS1 = 0.f;
    float aV2x = 0.f, aV2y = 0.f, aV2z = 0.f;
    float aV3x = 0.f, aV3y = 0.f, aV3z = 0.f;

    int src_next = (sbeg < send) ? srcs[sbeg] : 0;
    for (int i = sbeg; i < send; i++) {
        int src = src_next;
        if (i + 1 < send) src_next = srcs[i + 1];
        U2 wq;
        wq.v = __builtin_nontemporal_load((const uint2x*)(w_pk + ((size_t)i * 128 + u) * 4));
        ushort4 yq = *(const ushort4*)(y_pk + ((size_t)src * 128 + u) * 4);
        float4 ea = *(const float4*)(ea_sorted + (size_t)i * 4);
        float wss = bf2f(wq.us[0]), wsv = bf2f(wq.us[1]);
        float wvs = bf2f(wq.us[2]), wvv = bf2f(wq.us[3]);
        float qs = bf2f(yq.x), q0 = bf2f(yq.y), q1 = bf2f(yq.z), q2 = bf2f(yq.w);
        aS0 += wss * qs * ea.x;
        aS1 += wvv * (q0*ea.y + q1*ea.z + q2*ea.w);
        float tsv = wsv * qs;
        aV2x += tsv * ea.y; aV2y += tsv * ea.z; aV2z += tsv * ea.w;
        float tvs = wvs * ea.x;
        aV3x += tvs * q0; aV3y += tvs * q1; aV3z += tvs * q2;
    }

    const float inv = 0.25f;                 // 1/sqrt(16)
    const float s1c = 0.57735026919f * 0.25f;
    accS[(size_t)n * 256 + u]       = aS0 * inv;
    accS[(size_t)n * 256 + 128 + u] = aS1 * s1c;
    float* av0 = accV + ((size_t)n * 3 + 0) * 256;
    float* av1 = accV + ((size_t)n * 3 + 1) * 256;
    float* av2 = accV + ((size_t)n * 3 + 2) * 256;
    av0[u] = aV2x * inv;  av0[128 + u] = aV3x * inv;
    av1[u] = aV2y * inv;  av1[128 + u] = aV3y * inv;
    av2[u] = aV2z * inv;  av2[128 + u] = aV3z * inv;
}

// ---------------- pack_b: B matrices -> bf16, MFMA B-fragment order ----------------
__global__ __launch_bounds__(256) void pack_b_kernel(
    const float* __restrict__ sc_ws, const float* __restrict__ lin2_ws,
    const float* __restrict__ sc_wv, const float* __restrict__ lin2_wv,
    unsigned short* __restrict__ b_pre)
{
    int id = blockIdx.x * 256 + threadIdx.x;     // 0..49151
    int mat = id / 24576;
    int slot = id - mat * 24576;
    int ks = slot >> 9;
    int rr = slot & 511;
    int lane = rr & 63;
    int quad = lane >> 4;
    int n = ((rr >> 6) << 4) + (lane & 15);
    const float* sc  = mat ? sc_wv  : sc_ws;
    const float* lin = mat ? lin2_wv : lin2_ws;
    S8 pk;
    #pragma unroll
    for (int j = 0; j < 8; j++) {
        int k = ks * 32 + quad * 8 + j;
        float w;
        if (k < 1280) {
            int u = k & 127, v = k >> 7;
            w = sc[(u * 10 + v) * 128 + n];
        } else {
            w = lin[(k - 1280) * 128 + n];
        }
        pk.u[j] = f2bf(w);
    }
    *(uint4*)(b_pre + (size_t)id * 8) = pk.q;
}

// ---------------- node_out as MFMA GEMM (planar A, 128-row M-tile) ----------------
__global__ __launch_bounds__(256) void node_out_mfma(
    const float* __restrict__ node_feats,
    const float* __restrict__ node_attrs,
    const unsigned short* __restrict__ xvP16,
    const float* __restrict__ accS,
    const float* __restrict__ accV,
    const unsigned short* __restrict__ b_pre,
    float* __restrict__ out)
{
    __shared__ short8x Al[512];     // 128 rows x 32 k (8 KB)
    const int bid = blockIdx.x;
    const int t = threadIdx.x;
    const int lane = t & 63;
    const int wv = t >> 6;
    const bool is_s = (bid < S_BLK);

    const int r0g = t >> 2;
    const int q = t & 3;
    const float* pxA[2];
    const unsigned short* pxvA[2];
    const float* paA[2];
    const float* patA[2];
    #pragma unroll
    for (int j = 0; j < 2; j++) {
        int r = r0g + j * 64;
        if (is_s) {
            int R = bid * 128 + r;
            int node = (R < N_NODES) ? R : 0;
            pxA[j]  = node_feats + (size_t)node * 512;
            pxvA[j] = nullptr;
            paA[j]  = accS + (size_t)node * 256;
            patA[j] = node_attrs + node * 10;
        } else {
            int Rg = (bid - S_BLK) * 128 + r;
            if (Rg >= 3 * N_NODES) Rg = 0;
            int node = Rg / 3;
            pxA[j]  = nullptr;
            pxvA[j] = xvP16 + (size_t)Rg * 128;
            paA[j]  = accV + (size_t)Rg * 256;
            patA[j] = node_attrs + node * 10;
        }
    }
    int aslot[2];
    #pragma unroll
    for (int j = 0; j < 2; j++) {
        int r = r0g + j * 64;
        aslot[j] = ((r >> 4) << 6) + (q << 4) + (r & 15);
    }

    const uint4* bfrag_base = (const uint4*)(b_pre) + (is_s ? 0 : 24576);
    const float sc_norm = 0.02795084972f;   // 1/sqrt(1280)
    const float l2 = 0.0625f;               // 1/sqrt(256)

    floatx4 c[8][2];
    #pragma unroll
    for (int af = 0; af < 8; af++) {
        c[af][0] = (floatx4){0.f, 0.f, 0.f, 0.f};
        c[af][1] = (floatx4){0.f, 0.f, 0.f, 0.f};
    }

    for (int ks = 0; ks < 48; ks++) {
        S8 b0, b1;
        b0.q = bfrag_base[ks*512 + (wv*2+0)*64 + lane];
        b1.q = bfrag_base[ks*512 + (wv*2+1)*64 + lane];

        __syncthreads();
        {
            int k0 = ks * 32 + q * 8;
            #pragma unroll
            for (int j = 0; j < 2; j++) {
                S8 pk;
                if (k0 < 1280) {
                    int u0 = k0 & 127;
                    float att = patA[j][k0 >> 7] * sc_norm;
                    if (is_s) {
                        #pragma unroll
                        for (int i = 0; i < 8; i++)
                            pk.u[i] = f2bf(pxA[j][u0 + i] * att);
                    } else {
                        #pragma unroll
                        for (int i = 0; i < 8; i++)
                            pk.u[i] = f2bf(bf2f(pxvA[j][u0 + i]) * att);
                    }
                } else {
                    int j2 = k0 - 1280;
                    #pragma unroll
                    for (int i = 0; i < 8; i++)
                        pk.u[i] = f2bf(paA[j][j2 + i] * l2);
                }
                Al[aslot[j]] = pk.v;
            }
        }
        __syncthreads();

        #pragma unroll
        for (int af = 0; af < 8; af++) {
            short8x a = Al[af*64 + lane];
            c[af][0] = __builtin_amdgcn_mfma_f32_16x16x32_bf16(a, b0.v, c[af][0], 0, 0, 0);
            c[af][1] = __builtin_amdgcn_mfma_f32_16x16x32_bf16(a, b1.v, c[af][1], 0, 0, 0);
        }
    }

    const int m = lane & 15;
    const int rq = (lane >> 4) * 4;
    if (is_s) {
        const int n0 = bid * 128;
        #pragma unroll
        for (int af = 0; af < 8; af++) {
            #pragma unroll
            for (int i = 0; i < 4; i++) {
                int n = n0 + af*16 + rq + i;
                if (n < N_NODES) {
                    out[(size_t)n*512 + wv*32 + m]      = c[af][0][i];
                    out[(size_t)n*512 + wv*32 + 16 + m] = c[af][1][i];
                }
            }
        }
    } else {
        const int r0 = (bid - S_BLK) * 128;
        #pragma unroll
        for (int af = 0; af < 8; af++) {
            #pragma unroll
            for (int i = 0; i < 4; i++) {
                int Rg = r0 + af*16 + rq + i;
                if (Rg < 3 * N_NODES) {
                    int nn = Rg / 3;
                    int cc = Rg - nn * 3;
                    float* po = out + (size_t)nn*512 + 128 + cc;
                    po[(wv*32 + m)*3]      = c[af][0][i];
                    po[(wv*32 + 16 + m)*3] = c[af][1][i];
                }
            }
        }
    }
}

extern "C" void kernel_launch(void* const* d_in, const int* in_sizes, int n_in,
                              void* d_out, int out_size, void* d_ws, size_t ws_size,
                              hipStream_t stream) {
    const float* node_feats = (const float*)d_in[0];
    const float* node_attrs = (const float*)d_in[1];
    const float* edge_feats = (const float*)d_in[2];
    const float* edge_attrs = (const float*)d_in[3];
    const int*   edge_index = (const int*)  d_in[4];
    const float* lin1_ws    = (const float*)d_in[5];
    const float* lin1_wv    = (const float*)d_in[6];
    const float* fc_w0      = (const float*)d_in[7];
    const float* fc_w1      = (const float*)d_in[8];
    const float* fc_w2      = (const float*)d_in[9];
    const float* lin2_ws    = (const float*)d_in[10];
    const float* lin2_wv    = (const float*)d_in[11];
    const float* sc_ws      = (const float*)d_in[12];
    const float* sc_wv      = (const float*)d_in[13];
    float* out = (float*)d_out;

    // workspace layout
    unsigned short* y_pk  = (unsigned short*)d_ws;            // 5,120,000 us
    float* accS = (float*)(y_pk + (size_t)5120000);           // 2,560,000 f32
    float* accV = accS + (size_t)2560000;                     // 7,680,000 f32
    unsigned short* xvP16 = (unsigned short*)(accV + (size_t)7680000);  // 3,840,000 us
    unsigned short* w_pk  = xvP16 + (size_t)3840000;          // 81,920,000 us
    int* deg       = (int*)(w_pk + (size_t)81920000);
    int* row_start = deg + 10016;
    int* cursor    = row_start + 10016;
    int* edge_list = cursor + 10016;
    int* srcs      = edge_list + N_EDGES;
    float* ea_sorted = (float*)(srcs + N_EDGES);
    unsigned short* b_pre = (unsigned short*)(ea_sorted + (size_t)N_EDGES * 4);
    unsigned short* w2a   = b_pre + (size_t)2 * 24576 * 8;
    unsigned short* w1a   = w2a + (size_t)4096 * 8;
    unsigned short* b_lin = w1a + (size_t)512 * 8;
    const size_t need = (size_t)5120000 * 2 + (size_t)(2560000 + 7680000) * 4
                      + (size_t)3840000 * 2 + (size_t)81920000 * 2
                      + (size_t)(10016 * 3 + N_EDGES * 2) * 4
                      + (size_t)N_EDGES * 4 * 4
                      + ((size_t)2 * 24576 * 8 + (size_t)4096 * 8 + (size_t)512 * 8
                         + (size_t)4096 * 8) * 2;
    if (ws_size < need) return;

    hipLaunchKernelGGL(pack_b_kernel, dim3(192), dim3(256), 0, stream,
                       sc_ws, lin2_ws, sc_wv, lin2_wv, b_pre);
    hipLaunchKernelGGL(pack_w2a_kernel, dim3(16), dim3(256), 0, stream, fc_w2, w2a);
    hipLaunchKernelGGL(pack_w1a_kernel, dim3(2), dim3(256), 0, stream, fc_w1, w1a);
    hipLaunchKernelGGL(pack_lin1b_kernel, dim3(16), dim3(256), 0, stream,
                       lin1_ws, lin1_wv, b_lin);
    hipLaunchKernelGGL(node_lin1_mfma, dim3(313), dim3(256), 0, stream,
                       node_feats, b_lin, y_pk, xvP16);

    hipMemsetAsync(deg, 0, (size_t)N_NODES * sizeof(int), stream);
    hipLaunchKernelGGL(hist_kernel, dim3(625), dim3(256), 0, stream, edge_index, deg);
    hipLaunchKernelGGL(scan_kernel, dim3(1), dim3(1024), 0, stream, deg, row_start, cursor);
    hipLaunchKernelGGL(scatter_kernel, dim3(625), dim3(256), 0, stream,
                       edge_index, edge_attrs, cursor, edge_list, srcs, ea_sorted);
    hipLaunchKernelGGL(edge_w_mfma, dim3(2500), dim3(256), 0, stream,
                       edge_feats, edge_list, fc_w0, w1a, w2a, w_pk);
    hipLaunchKernelGGL(gather_kernel, dim3(5000), dim3(256), 0, stream,
                       row_start, srcs, ea_sorted, w_pk, y_pk, accS, accV);

    hipLaunchKernelGGL(node_out_mfma, dim3(S_BLK + V_BLK), dim3(256), 0, stream,
                       node_feats, node_attrs, xvP16, accS, accV, b_pre, out);
}

// Round 11
// 342.714 us; speedup vs baseline: 2.0243x; 1.0118x over previous
//
#include <hip/hip_runtime.h>
#include <hip/hip_bf16.h>
#include <math.h>

#define N_NODES 10000
#define N_EDGES 160000
#define S_BLK 79            // ceil(10000/128) s-GEMM blocks
#define V_BLK 235           // ceil(30000/128) v-GEMM blocks

typedef __attribute__((ext_vector_type(8))) short short8x;
typedef __attribute__((ext_vector_type(4))) float floatx4;
typedef __attribute__((ext_vector_type(4))) unsigned int uint4x;
typedef __attribute__((ext_vector_type(2))) unsigned int uint2x;

union S8 { short8x v; unsigned short u[8]; uint4 q; };
union U2 { uint2x v; unsigned short us[4]; };

__device__ __forceinline__ unsigned short f2bf(float x) {
    unsigned int u = __float_as_uint(x);
    return (unsigned short)((u + 0x7fffu + ((u >> 16) & 1u)) >> 16);
}
__device__ __forceinline__ float bf2f(unsigned short u) {
    return __uint_as_float(((unsigned)u) << 16);
}
__device__ __forceinline__ float silu_c(float x) {
    return 1.679f * x / (1.0f + __expf(-x));
}

// ---------------- pack_all: all weight pre-packs in one launch ----------------
// blocks [0,192): b_pre; [192,208): w2a; [208,210): w1a; [210,226): b_lin
__global__ __launch_bounds__(256) void pack_all_kernel(
    const float* __restrict__ sc_ws, const float* __restrict__ lin2_ws,
    const float* __restrict__ sc_wv, const float* __restrict__ lin2_wv,
    const float* __restrict__ fc_w2, const float* __restrict__ fc_w1,
    const float* __restrict__ lin1_ws, const float* __restrict__ lin1_wv,
    unsigned short* __restrict__ b_pre, unsigned short* __restrict__ w2a,
    unsigned short* __restrict__ w1a, unsigned short* __restrict__ b_lin)
{
    const int bid = blockIdx.x;
    const int t = threadIdx.x;
    if (bid < 192) {
        int id = bid * 256 + t;                  // 0..49151
        int mat = id / 24576;
        int slot = id - mat * 24576;
        int ks = slot >> 9;
        int rr = slot & 511;
        int lane = rr & 63;
        int quad = lane >> 4;
        int n = ((rr >> 6) << 4) + (lane & 15);
        const float* sc  = mat ? sc_wv  : sc_ws;
        const float* lin = mat ? lin2_wv : lin2_ws;
        S8 pk;
        #pragma unroll
        for (int j = 0; j < 8; j++) {
            int k = ks * 32 + quad * 8 + j;
            float w;
            if (k < 1280) {
                int u = k & 127, v = k >> 7;
                w = sc[(u * 10 + v) * 128 + n];
            } else {
                w = lin[(k - 1280) * 128 + n];
            }
            pk.u[j] = f2bf(w);
        }
        *(uint4*)(b_pre + (size_t)id * 8) = pk.q;
    } else if (bid < 208) {
        int id = (bid - 192) * 256 + t;          // 0..4095
        int lane = id & 63;
        int mfg = (id >> 6) & 31;
        int ks = id >> 11;
        int col = mfg * 16 + (lane & 15);
        int k0 = ks * 32 + (lane >> 4) * 8;
        S8 pk;
        #pragma unroll
        for (int j = 0; j < 8; j++)
            pk.u[j] = f2bf(fc_w2[(k0 + j) * 512 + col] * 0.125f);
        *(uint4*)(w2a + (size_t)id * 8) = pk.q;
    } else if (bid < 210) {
        int id = (bid - 208) * 256 + t;          // 0..511
        int lane = id & 63;
        int mf = (id >> 6) & 3;
        int ks = id >> 8;
        int m = mf * 16 + (lane & 15);
        int k0 = ks * 32 + (lane >> 4) * 8;
        S8 pk;
        #pragma unroll
        for (int j = 0; j < 8; j++)
            pk.u[j] = f2bf(fc_w1[(k0 + j) * 64 + m] * 0.125f);
        *(uint4*)(w1a + (size_t)id * 8) = pk.q;
    } else {
        int id = (bid - 210) * 256 + t;          // 0..4095
        int mat = id >> 11;
        int slot = id & 2047;
        int ks = slot >> 9;
        int rr = slot & 511;
        int nf = rr >> 6;
        int lane = rr & 63;
        int n = nf * 16 + (lane & 15);
        int k0 = ks * 32 + (lane >> 4) * 8;
        const float* w = mat ? lin1_wv : lin1_ws;
        const float l1 = 0.0883883476483f;
        S8 pk;
        #pragma unroll
        for (int j = 0; j < 8; j++)
            pk.u[j] = f2bf(w[(k0 + j) * 128 + n] * l1);
        *(uint4*)(b_lin + (size_t)id * 8) = pk.q;
    }
}

// ---------------- Kernel A: lin1 via MFMA -> packed bf16 y + bf16 xvP ----------------
__global__ __launch_bounds__(256) void node_lin1_mfma(
    const float* __restrict__ node_feats,
    const unsigned short* __restrict__ b_lin,
    unsigned short* __restrict__ y_pk,
    unsigned short* __restrict__ xvP16)
{
    __shared__ __align__(16) unsigned char smem[32768];
    short8x* Al = (short8x*)smem;
    unsigned short* Yt = (unsigned short*)smem;

    const int blk = blockIdx.x;   // 313
    const int t = threadIdx.x;
    const int base = blk * 32;
    const int lane = t & 63;
    const int wv = t >> 6;
    const int m15 = lane & 15;
    const int k0q = (lane >> 4) * 8;

    #pragma unroll
    for (int it = 0; it < 8; it++) {
        int g = wv * 8 + it;
        int af = g >> 2;
        int ks = g & 3;
        int m = af * 16 + m15;
        int comp = m >> 5;
        int nloc = m & 31;
        int node = base + nloc;
        int valid = (node < N_NODES);
        if (!valid) node = N_NODES - 1;
        int k0 = ks * 32 + k0q;
        const float* row = node_feats + (size_t)node * 512;
        S8 pk;
        if (comp == 0) {
            float4 a = *(const float4*)&row[k0];
            float4 b = *(const float4*)&row[k0 + 4];
            pk.u[0] = f2bf(a.x); pk.u[1] = f2bf(a.y); pk.u[2] = f2bf(a.z); pk.u[3] = f2bf(a.w);
            pk.u[4] = f2bf(b.x); pk.u[5] = f2bf(b.y); pk.u[6] = f2bf(b.z); pk.u[7] = f2bf(b.w);
        } else {
            int c = comp - 1;
            #pragma unroll
            for (int j = 0; j < 8; j++)
                pk.u[j] = f2bf(row[128 + (k0 + j) * 3 + c]);
            if (valid)
                *(uint4*)&xvP16[((size_t)node * 3 + c) * 128 + k0] = pk.q;
        }
        Al[(ks * 8 + af) * 64 + lane] = pk.v;
    }
    __syncthreads();

    floatx4 c[8][2];
    #pragma unroll
    for (int af = 0; af < 8; af++) {
        c[af][0] = (floatx4){0.f, 0.f, 0.f, 0.f};
        c[af][1] = (floatx4){0.f, 0.f, 0.f, 0.f};
    }

    const uint4* bq = (const uint4*)b_lin;
    #pragma unroll
    for (int ks = 0; ks < 4; ks++) {
        S8 bs0, bs1, bv0, bv1;
        bs0.q = bq[       ks*512 + (wv*2+0)*64 + lane];
        bs1.q = bq[       ks*512 + (wv*2+1)*64 + lane];
        bv0.q = bq[2048 + ks*512 + (wv*2+0)*64 + lane];
        bv1.q = bq[2048 + ks*512 + (wv*2+1)*64 + lane];
        #pragma unroll
        for (int af = 0; af < 8; af++) {
            short8x a = Al[(ks*8 + af)*64 + lane];
            if (af < 2) {
                c[af][0] = __builtin_amdgcn_mfma_f32_16x16x32_bf16(a, bs0.v, c[af][0], 0, 0, 0);
                c[af][1] = __builtin_amdgcn_mfma_f32_16x16x32_bf16(a, bs1.v, c[af][1], 0, 0, 0);
            } else {
                c[af][0] = __builtin_amdgcn_mfma_f32_16x16x32_bf16(a, bv0.v, c[af][0], 0, 0, 0);
                c[af][1] = __builtin_amdgcn_mfma_f32_16x16x32_bf16(a, bv1.v, c[af][1], 0, 0, 0);
            }
        }
    }
    __syncthreads();

    {
        const int rq = (lane >> 4) * 4;
        #pragma unroll
        for (int af = 0; af < 8; af++) {
            #pragma unroll
            for (int nf = 0; nf < 2; nf++) {
                int u = wv * 32 + nf * 16 + m15;
                #pragma unroll
                for (int i = 0; i < 4; i++) {
                    int m = af * 16 + rq + i;
                    int comp = m >> 5, nloc = m & 31;
                    Yt[(nloc * 128 + u) * 4 + comp] = f2bf(c[af][nf][i]);
                }
            }
        }
    }
    __syncthreads();
    {
        unsigned short* dst = y_pk + (size_t)base * 512;
        int nrem = N_NODES - base;
        #pragma unroll
        for (int it = 0; it < 8; it++) {
            int idx = it * 256 + t;
            if ((idx >> 6) < nrem)
                *(uint4*)(dst + (size_t)idx * 8) = *(const uint4*)&Yt[idx * 8];
        }
    }
}

// ---------------- CSR build ----------------
__global__ __launch_bounds__(256) void hist_kernel(const int* __restrict__ edge_index,
                                                   int* __restrict__ deg) {
    int e = blockIdx.x * 256 + threadIdx.x;
    if (e < N_EDGES) atomicAdd(&deg[edge_index[e]], 1);
}

__global__ __launch_bounds__(1024) void scan_kernel(const int* __restrict__ deg,
                                                    int* __restrict__ row_start,
                                                    int* __restrict__ cursor) {
    __shared__ int wsum[16];
    __shared__ int carry_s;
    const int t = threadIdx.x;
    const int lane = t & 63, w = t >> 6;
    if (t == 0) carry_s = 0;
    __syncthreads();
    for (int chunk = 0; chunk < 10; chunk++) {
        int idx = chunk * 1024 + t;
        int v = (idx < N_NODES) ? deg[idx] : 0;
        int x = v;
        #pragma unroll
        for (int off = 1; off < 64; off <<= 1) {
            int yv = __shfl_up(x, off, 64);
            if (lane >= off) x += yv;
        }
        if (lane == 63) wsum[w] = x;
        __syncthreads();
        int wpre = 0;
        for (int i = 0; i < w; i++) wpre += wsum[i];
        int incl = x + wpre + carry_s;
        int excl = incl - v;
        if (idx < N_NODES) { row_start[idx] = excl; cursor[idx] = excl; }
        __syncthreads();
        if (t == 1023) carry_s = incl;
        __syncthreads();
    }
    if (t == 0) row_start[N_NODES] = carry_s;
}

__global__ __launch_bounds__(256) void scatter_kernel(const int* __restrict__ edge_index,
                                                      const float* __restrict__ edge_attrs,
                                                      int* __restrict__ cursor,
                                                      int* __restrict__ edge_list,
                                                      int* __restrict__ srcs,
                                                      float* __restrict__ ea_sorted) {
    int e = blockIdx.x * 256 + threadIdx.x;
    if (e < N_EDGES) {
        int pos = atomicAdd(&cursor[edge_index[e]], 1);
        edge_list[pos] = e;
        srcs[pos] = edge_index[N_EDGES + e];
        float4 ea = *(const float4*)(edge_attrs + (size_t)e * 4);
        *(float4*)(ea_sorted + (size_t)pos * 4) = ea;
    }
}

// ---------------- Kernel B1: edge MLP (sorted order) -> packed bf16 w ----------------
// w_pk[pos][u][4] = bf16{ss, sv, vs, vv}
// LDS 26.4 KB -> 6 blocks/CU; phase 3 in 4 passes of 2 m-frags (32 acc VGPRs)
__global__ __launch_bounds__(256) void edge_w_mfma(
    const float* __restrict__ edge_feats,
    const int* __restrict__ edge_list,
    const float* __restrict__ fc_w0,
    const unsigned short* __restrict__ w1a,
    const unsigned short* __restrict__ w2a,
    unsigned short* __restrict__ w_pk)
{
    __shared__ __align__(16) unsigned char smem[26368];
    float* ef = (float*)smem;                               // [0, 2304)
    unsigned short* h0b = (unsigned short*)(smem + 2304);   // [2304, 11520): 64 x 72
    unsigned short* T   = (unsigned short*)smem;            // [0, 16896): 64 x 132 (epilogue)
    unsigned short* h1b = (unsigned short*)(smem + 16896);  // [16896, 26112): 64 x 72
    int* eids = (int*)(smem + 26112);                       // [26112, 26368)

    const int blk = blockIdx.x;      // 2500
    const int t = threadIdx.x;
    const int eb0 = blk * 64;
    const int lane = t & 63;
    const int wv = t >> 6;
    const int quad = lane >> 4;
    const int m15 = lane & 15;

    if (t < 64) eids[t] = edge_list[eb0 + t];
    __syncthreads();

    #pragma unroll
    for (int r = 0; r < 2; r++) {
        int idx = r * 256 + t;
        int el = idx >> 3;
        int k = idx & 7;
        ef[el * 9 + k] = edge_feats[(size_t)eids[el] * 8 + k];
    }
    __syncthreads();

    // phase 1 (VALU, f32): h0 = silu_c(ef @ w0 / sqrt(8)) -> bf16
    {
        const int e_loc = t >> 2;
        const int c0 = (t & 3) * 16;
        float a0[16];
        #pragma unroll
        for (int i = 0; i < 16; i++) a0[i] = 0.f;
        const float* efr = &ef[e_loc * 9];
        #pragma unroll
        for (int k = 0; k < 8; k++) {
            float ek = efr[k];
            float w[16];
            #pragma unroll
            for (int q4 = 0; q4 < 4; q4++)
                *(float4*)&w[q4*4] = *(const float4*)&fc_w0[k*64 + c0 + q4*4];
            #pragma unroll
            for (int i = 0; i < 16; i++) a0[i] += ek * w[i];
        }
        const float is8 = 0.35355339059f;
        S8 p0, p1;
        #pragma unroll
        for (int i = 0; i < 8; i++) {
            p0.u[i] = f2bf(silu_c(a0[i] * is8));
            p1.u[i] = f2bf(silu_c(a0[8 + i] * is8));
        }
        *(uint4*)&h0b[e_loc * 72 + c0]     = p0.q;
        *(uint4*)&h0b[e_loc * 72 + c0 + 8] = p1.q;
    }
    __syncthreads();

    // phase 2 (MFMA): h1 = silu_c(h0 @ w1 / 8)
    {
        floatx4 c2[4];
        #pragma unroll
        for (int ee = 0; ee < 4; ee++) c2[ee] = (floatx4){0.f, 0.f, 0.f, 0.f};
        const uint4* w1aq = (const uint4*)w1a;
        #pragma unroll
        for (int ks = 0; ks < 2; ks++) {
            S8 afr;
            afr.q = w1aq[(ks*4 + wv)*64 + lane];
            #pragma unroll
            for (int ee = 0; ee < 4; ee++) {
                S8 bfr;
                bfr.q = *(const uint4*)&h0b[(ee*16 + m15) * 72 + ks*32 + quad*8];
                c2[ee] = __builtin_amdgcn_mfma_f32_16x16x32_bf16(afr.v, bfr.v, c2[ee], 0, 0, 0);
            }
        }
        #pragma unroll
        for (int ee = 0; ee < 4; ee++) {
            ushort4 pk = make_ushort4(f2bf(silu_c(c2[ee][0])), f2bf(silu_c(c2[ee][1])),
                                      f2bf(silu_c(c2[ee][2])), f2bf(silu_c(c2[ee][3])));
            *(ushort4*)&h1b[(ee*16 + m15) * 72 + wv*16 + quad*4] = pk;
        }
    }
    __syncthreads();

    // phase 3 (MFMA, 4 passes of 2 m-frags); pass p covers cols p*32..p*32+31 of comp wv
    const uint4* w2aq = (const uint4*)w2a;
    #pragma unroll 1
    for (int p = 0; p < 4; p++) {
        floatx4 c3[2][4];
        #pragma unroll
        for (int mf = 0; mf < 2; mf++)
            #pragma unroll
            for (int ee = 0; ee < 4; ee++)
                c3[mf][ee] = (floatx4){0.f, 0.f, 0.f, 0.f};

        #pragma unroll
        for (int ks = 0; ks < 2; ks++) {
            S8 bfr[4];
            #pragma unroll
            for (int ee = 0; ee < 4; ee++)
                bfr[ee].q = *(const uint4*)&h1b[(ee*16 + m15) * 72 + ks*32 + quad*8];
            #pragma unroll
            for (int mf = 0; mf < 2; mf++) {
                S8 afr;
                afr.q = w2aq[(size_t)(ks*32 + wv*8 + p*2 + mf) * 64 + lane];
                #pragma unroll
                for (int ee = 0; ee < 4; ee++)
                    c3[mf][ee] = __builtin_amdgcn_mfma_f32_16x16x32_bf16(afr.v, bfr[ee].v, c3[mf][ee], 0, 0, 0);
            }
        }

        __syncthreads();   // T region free (prev pass stores done / ef+h0b dead)
        // dump interleaved: T[e*132 + col'*4 + comp], comp = wv
        #pragma unroll
        for (int mf = 0; mf < 2; mf++) {
            #pragma unroll
            for (int ee = 0; ee < 4; ee++) {
                int e = ee*16 + m15;
                #pragma unroll
                for (int i = 0; i < 4; i++) {
                    int colp = mf*16 + quad*4 + i;
                    T[e*132 + colp*4 + wv] = f2bf(c3[mf][ee][i]);
                }
            }
        }
        __syncthreads();

        // coalesced store: uint2 per (e, cu); per e-row 256 B contiguous
        #pragma unroll
        for (int it = 0; it < 8; it++) {
            int idx = it * 256 + t;          // 0..2047
            int e  = idx >> 5;
            int cu = idx & 31;
            uint2x v = *(const uint2x*)&T[e*132 + cu*4];
            unsigned short* dstp = w_pk + ((size_t)(eb0 + e) * 128 + p*32 + cu) * 4;
            __builtin_nontemporal_store(v, (uint2x*)dstp);
        }
    }
}

// ---------------- Kernel B2: per-node gather, software-pipelined ----------------
__global__ __launch_bounds__(256) void gather_kernel(
    const int* __restrict__ row_start,
    const int* __restrict__ srcs,
    const float* __restrict__ ea_sorted,
    const unsigned short* __restrict__ w_pk,
    const unsigned short* __restrict__ y_pk,
    float* __restrict__ accS,
    float* __restrict__ accV)
{
    const int t = threadIdx.x;
    const int half = t >> 7;
    const int u = t & 127;
    const int n = blockIdx.x * 2 + half;   // 5000 blocks
    const int sbeg = row_start[n];
    const int send = row_start[n + 1];

    float aS0 = 0.f, aS1 = 0.f;
    float aV2x = 0.f, aV2y = 0.f, aV2z = 0.f;
    float aV3x = 0.f, aV3y = 0.f, aV3z = 0.f;

    U2 wq_n; ushort4 yq_n; float4 ea_n;
    wq_n.v = (uint2x){0u, 0u};
    yq_n = make_ushort4(0, 0, 0, 0);
    ea_n = make_float4(0.f, 0.f, 0.f, 0.f);
    if (sbeg < send) {
        wq_n.v = __builtin_nontemporal_load((const uint2x*)(w_pk + ((size_t)sbeg * 128 + u) * 4));
        int s0 = srcs[sbeg];
        yq_n = *(const ushort4*)(y_pk + ((size_t)s0 * 128 + u) * 4);
        ea_n = *(const float4*)(ea_sorted + (size_t)sbeg * 4);
    }
    for (int i = sbeg; i < send; i++) {
        U2 wq = wq_n; ushort4 yq = yq_n; float4 ea = ea_n;
        int inx = i + 1;
        if (inx < send) {
            wq_n.v = __builtin_nontemporal_load((const uint2x*)(w_pk + ((size_t)inx * 128 + u) * 4));
            int s1 = srcs[inx];
            yq_n = *(const ushort4*)(y_pk + ((size_t)s1 * 128 + u) * 4);
            ea_n = *(const float4*)(ea_sorted + (size_t)inx * 4);
        }
        float wss = bf2f(wq.us[0]), wsv = bf2f(wq.us[1]);
        float wvs = bf2f(wq.us[2]), wvv = bf2f(wq.us[3]);
        float qs = bf2f(yq.x), q0 = bf2f(yq.y), q1 = bf2f(yq.z), q2 = bf2f(yq.w);
        aS0 += wss * qs * ea.x;
        aS1 += wvv * (q0*ea.y + q1*ea.z + q2*ea.w);
        float tsv = wsv * qs;
        aV2x += tsv * ea.y; aV2y += tsv * ea.z; aV2z += tsv * ea.w;
        float tvs = wvs * ea.x;
        aV3x += tvs * q0; aV3y += tvs * q1; aV3z += tvs * q2;
    }

    const float inv = 0.25f;                 // 1/sqrt(16)
    const float s1c = 0.57735026919f * 0.25f;
    accS[(size_t)n * 256 + u]       = aS0 * inv;
    accS[(size_t)n * 256 + 128 + u] = aS1 * s1c;
    float* av0 = accV + ((size_t)n * 3 + 0) * 256;
    float* av1 = accV + ((size_t)n * 3 + 1) * 256;
    float* av2 = accV + ((size_t)n * 3 + 2) * 256;
    av0[u] = aV2x * inv;  av0[128 + u] = aV3x * inv;
    av1[u] = aV2y * inv;  av1[128 + u] = aV3y * inv;
    av2[u] = aV2z * inv;  av2[128 + u] = aV3z * inv;
}

// ---------------- node_out as MFMA GEMM (planar A, 128-row M-tile) ----------------
__global__ __launch_bounds__(256) void node_out_mfma(
    const float* __restrict__ node_feats,
    const float* __restrict__ node_attrs,
    const unsigned short* __restrict__ xvP16,
    const float* __restrict__ accS,
    const float* __restrict__ accV,
    const unsigned short* __restrict__ b_pre,
    float* __restrict__ out)
{
    __shared__ short8x Al[512];     // 128 rows x 32 k (8 KB)
    const int bid = blockIdx.x;
    const int t = threadIdx.x;
    const int lane = t & 63;
    const int wv = t >> 6;
    const bool is_s = (bid < S_BLK);

    const int r0g = t >> 2;
    const int q = t & 3;
    const float* pxA[2];
    const unsigned short* pxvA[2];
    const float* paA[2];
    const float* patA[2];
    #pragma unroll
    for (int j = 0; j < 2; j++) {
        int r = r0g + j * 64;
        if (is_s) {
            int R = bid * 128 + r;
            int node = (R < N_NODES) ? R : 0;
            pxA[j]  = node_feats + (size_t)node * 512;
            pxvA[j] = nullptr;
            paA[j]  = accS + (size_t)node * 256;
            patA[j] = node_attrs + node * 10;
        } else {
            int Rg = (bid - S_BLK) * 128 + r;
            if (Rg >= 3 * N_NODES) Rg = 0;
            int node = Rg / 3;
            pxA[j]  = nullptr;
            pxvA[j] = xvP16 + (size_t)Rg * 128;
            paA[j]  = accV + (size_t)Rg * 256;
            patA[j] = node_attrs + node * 10;
        }
    }
    int aslot[2];
    #pragma unroll
    for (int j = 0; j < 2; j++) {
        int r = r0g + j * 64;
        aslot[j] = ((r >> 4) << 6) + (q << 4) + (r & 15);
    }

    const uint4* bfrag_base = (const uint4*)(b_pre) + (is_s ? 0 : 24576);
    const float sc_norm = 0.02795084972f;   // 1/sqrt(1280)
    const float l2 = 0.0625f;               // 1/sqrt(256)

    floatx4 c[8][2];
    #pragma unroll
    for (int af = 0; af < 8; af++) {
        c[af][0] = (floatx4){0.f, 0.f, 0.f, 0.f};
        c[af][1] = (floatx4){0.f, 0.f, 0.f, 0.f};
    }

    for (int ks = 0; ks < 48; ks++) {
        S8 b0, b1;
        b0.q = bfrag_base[ks*512 + (wv*2+0)*64 + lane];
        b1.q = bfrag_base[ks*512 + (wv*2+1)*64 + lane];

        __syncthreads();
        {
            int k0 = ks * 32 + q * 8;
            #pragma unroll
            for (int j = 0; j < 2; j++) {
                S8 pk;
                if (k0 < 1280) {
                    int u0 = k0 & 127;
                    float att = patA[j][k0 >> 7] * sc_norm;
                    if (is_s) {
                        #pragma unroll
                        for (int i = 0; i < 8; i++)
                            pk.u[i] = f2bf(pxA[j][u0 + i] * att);
                    } else {
                        #pragma unroll
                        for (int i = 0; i < 8; i++)
                            pk.u[i] = f2bf(bf2f(pxvA[j][u0 + i]) * att);
                    }
                } else {
                    int j2 = k0 - 1280;
                    #pragma unroll
                    for (int i = 0; i < 8; i++)
                        pk.u[i] = f2bf(paA[j][j2 + i] * l2);
                }
                Al[aslot[j]] = pk.v;
            }
        }
        __syncthreads();

        #pragma unroll
        for (int af = 0; af < 8; af++) {
            short8x a = Al[af*64 + lane];
            c[af][0] = __builtin_amdgcn_mfma_f32_16x16x32_bf16(a, b0.v, c[af][0], 0, 0, 0);
            c[af][1] = __builtin_amdgcn_mfma_f32_16x16x32_bf16(a, b1.v, c[af][1], 0, 0, 0);
        }
    }

    const int m = lane & 15;
    const int rq = (lane >> 4) * 4;
    if (is_s) {
        const int n0 = bid * 128;
        #pragma unroll
        for (int af = 0; af < 8; af++) {
            #pragma unroll
            for (int i = 0; i < 4; i++) {
                int n = n0 + af*16 + rq + i;
                if (n < N_NODES) {
                    out[(size_t)n*512 + wv*32 + m]      = c[af][0][i];
                    out[(size_t)n*512 + wv*32 + 16 + m] = c[af][1][i];
                }
            }
        }
    } else {
        const int r0 = (bid - S_BLK) * 128;
        #pragma unroll
        for (int af = 0; af < 8; af++) {
            #pragma unroll
            for (int i = 0; i < 4; i++) {
                int Rg = r0 + af*16 + rq + i;
                if (Rg < 3 * N_NODES) {
                    int nn = Rg / 3;
                    int cc = Rg - nn * 3;
                    float* po = out + (size_t)nn*512 + 128 + cc;
                    po[(wv*32 + m)*3]      = c[af][0][i];
                    po[(wv*32 + 16 + m)*3] = c[af][1][i];
                }
            }
        }
    }
}

extern "C" void kernel_launch(void* const* d_in, const int* in_sizes, int n_in,
                              void* d_out, int out_size, void* d_ws, size_t ws_size,
                              hipStream_t stream) {
    const float* node_feats = (const float*)d_in[0];
    const float* node_attrs = (const float*)d_in[1];
    const float* edge_feats = (const float*)d_in[2];
    const float* edge_attrs = (const float*)d_in[3];
    const int*   edge_index = (const int*)  d_in[4];
    const float* lin1_ws    = (const float*)d_in[5];
    const float* lin1_wv    = (const float*)d_in[6];
    const float* fc_w0      = (const float*)d_in[7];
    const float* fc_w1      = (const float*)d_in[8];
    const float* fc_w2      = (const float*)d_in[9];
    const float* lin2_ws    = (const float*)d_in[10];
    const float* lin2_wv    = (const float*)d_in[11];
    const float* sc_ws      = (const float*)d_in[12];
    const float* sc_wv      = (const float*)d_in[13];
    float* out = (float*)d_out;

    // workspace layout
    unsigned short* y_pk  = (unsigned short*)d_ws;            // 5,120,000 us
    float* accS = (float*)(y_pk + (size_t)5120000);           // 2,560,000 f32
    float* accV = accS + (size_t)2560000;                     // 7,680,000 f32
    unsigned short* xvP16 = (unsigned short*)(accV + (size_t)7680000);  // 3,840,000 us
    unsigned short* w_pk  = xvP16 + (size_t)3840000;          // 81,920,000 us
    int* deg       = (int*)(w_pk + (size_t)81920000);
    int* row_start = deg + 10016;
    int* cursor    = row_start + 10016;
    int* edge_list = cursor + 10016;
    int* srcs      = edge_list + N_EDGES;
    float* ea_sorted = (float*)(srcs + N_EDGES);
    unsigned short* b_pre = (unsigned short*)(ea_sorted + (size_t)N_EDGES * 4);
    unsigned short* w2a   = b_pre + (size_t)2 * 24576 * 8;
    unsigned short* w1a   = w2a + (size_t)4096 * 8;
    unsigned short* b_lin = w1a + (size_t)512 * 8;
    const size_t need = (size_t)5120000 * 2 + (size_t)(2560000 + 7680000) * 4
                      + (size_t)3840000 * 2 + (size_t)81920000 * 2
                      + (size_t)(10016 * 3 + N_EDGES * 2) * 4
                      + (size_t)N_EDGES * 4 * 4
                      + ((size_t)2 * 24576 * 8 + (size_t)4096 * 8 + (size_t)512 * 8
                         + (size_t)4096 * 8) * 2;
    if (ws_size < need) return;

    hipLaunchKernelGGL(pack_all_kernel, dim3(226), dim3(256), 0, stream,
                       sc_ws, lin2_ws, sc_wv, lin2_wv, fc_w2, fc_w1, lin1_ws, lin1_wv,
                       b_pre, w2a, w1a, b_lin);
    hipLaunchKernelGGL(node_lin1_mfma, dim3(313), dim3(256), 0, stream,
                       node_feats, b_lin, y_pk, xvP16);

    hipMemsetAsync(deg, 0, (size_t)N_NODES * sizeof(int), stream);
    hipLaunchKernelGGL(hist_kernel, dim3(625), dim3(256), 0, stream, edge_index, deg);
    hipLaunchKernelGGL(scan_kernel, dim3(1), dim3(1024), 0, stream, deg, row_start, cursor);
    hipLaunchKernelGGL(scatter_kernel, dim3(625), dim3(256), 0, stream,
                       edge_index, edge_attrs, cursor, edge_list, srcs, ea_sorted);
    hipLaunchKernelGGL(edge_w_mfma, dim3(2500), dim3(256), 0, stream,
                       edge_feats, edge_list, fc_w0, w1a, w2a, w_pk);
    hipLaunchKernelGGL(gather_kernel, dim3(5000), dim3(256), 0, stream,
                       row_start, srcs, ea_sorted, w_pk, y_pk, accS, accV);

    hipLaunchKernelGGL(node_out_mfma, dim3(S_BLK + V_BLK), dim3(256), 0, stream,
                       node_feats, node_attrs, xvP16, accS, accV, b_pre, out);
}